// Round 1
// baseline (11530.589 us; speedup 1.0000x reference)
//
#include <hip/hip_runtime.h>
#include <math.h>

#define B 128
#define L 5000
#define DM 8
#define NL 4
#define DS 16
#define DI 16
#define HID 64
#define NC 230

__device__ __forceinline__ float sigmoidf_(float x){ return 1.f/(1.f+__expf(-x)); }
__device__ __forceinline__ float siluf_(float x){ return x*sigmoidf_(x); }
__device__ __forceinline__ float softplusf_(float x){ return fmaxf(x,0.f) + log1pf(__expf(-fabsf(x))); }

// ---------------- f = embed[idx] * x ----------------
__global__ void k_embed(const float* __restrict__ x, const int* __restrict__ idx,
                        const float* __restrict__ embed, float* __restrict__ f){
  int gid = blockIdx.x*256 + threadIdx.x; // b*L + t
  if (gid >= B*L) return;
  int t = gid % L;
  float xv = x[gid];
  const float* er = embed + (size_t)idx[t]*DM;
  float4 e0 = *(const float4*)(er);
  float4 e1 = *(const float4*)(er+4);
  float4 o0 = make_float4(e0.x*xv, e0.y*xv, e0.z*xv, e0.w*xv);
  float4 o1 = make_float4(e1.x*xv, e1.y*xv, e1.z*xv, e1.w*xv);
  *(float4*)(f + (size_t)gid*8)   = o0;
  *(float4*)(f + (size_t)gid*8+4) = o1;
}

// ---------------- per-layer: rmsnorm + in_proj + conv + silu + x_proj + dt ----------------
__global__ __launch_bounds__(256) void k_pre(const float* __restrict__ f,
                      const float* __restrict__ norm_w,   // 8
                      const float* __restrict__ in_proj,  // 32x8
                      const float* __restrict__ conv_w,   // 16x3
                      const float* __restrict__ conv_b,   // 16
                      const float* __restrict__ x_proj,   // 33x16
                      const float* __restrict__ dt_w,     // 16
                      const float* __restrict__ dt_b,     // 16
                      float* __restrict__ sz, float* __restrict__ u,
                      float* __restrict__ dl, float* __restrict__ Bv, float* __restrict__ Cv){
  __shared__ float s_nw[8], s_ip[256], s_cw[48], s_cb[16], s_xp[528], s_dtw[16], s_dtb[16];
  int tid = threadIdx.x;
  if (tid < 8) s_nw[tid] = norm_w[tid];
  s_ip[tid] = in_proj[tid];
  if (tid < 48) s_cw[tid] = conv_w[tid];
  if (tid < 16){ s_cb[tid]=conv_b[tid]; s_dtw[tid]=dt_w[tid]; s_dtb[tid]=dt_b[tid]; }
  for (int i = tid; i < 528; i += 256) s_xp[i] = x_proj[i];
  __syncthreads();

  int gid = blockIdx.x*256 + tid;
  int t = gid % L;

  float xc3[3][16];
  float xn[8];
  #pragma unroll
  for (int j=0;j<3;j++){
    int tau = t-2+j;
    if (tau < 0){
      #pragma unroll
      for(int c=0;c<16;c++) xc3[j][c]=0.f;
      continue;
    }
    const float* fr = f + (size_t)(gid + (j-2))*8;
    float fv[8]; float ss=0.f;
    #pragma unroll
    for(int d=0;d<8;d++){ fv[d]=fr[d]; ss += fv[d]*fv[d]; }
    float r = rsqrtf(ss*(1.f/8.f) + 1e-5f);
    #pragma unroll
    for(int d=0;d<8;d++) xn[d] = fv[d]*r*s_nw[d];
    #pragma unroll
    for(int c=0;c<16;c++){
      float a=0.f;
      #pragma unroll
      for(int d=0;d<8;d++) a += s_ip[c*8+d]*xn[d];
      xc3[j][c]=a;
    }
  }
  // conv + silu -> u
  float uu[16];
  #pragma unroll
  for(int c=0;c<16;c++){
    float a = s_cb[c] + s_cw[c*3+0]*xc3[0][c] + s_cw[c*3+1]*xc3[1][c] + s_cw[c*3+2]*xc3[2][c];
    uu[c] = siluf_(a);
  }
  // z (xn currently holds tau=t normalization)
  float szv[16];
  #pragma unroll
  for(int c=0;c<16;c++){
    float a=0.f;
    #pragma unroll
    for(int d=0;d<8;d++) a += s_ip[(16+c)*8+d]*xn[d];
    szv[c] = siluf_(a);
  }
  // x_proj: dbc[33]
  float dbc0=0.f;
  #pragma unroll
  for(int c=0;c<16;c++) dbc0 += s_xp[c]*uu[c];
  float dlv[16], Bn[16], Cn[16];
  #pragma unroll
  for(int n=0;n<16;n++){
    float a=0.f, cch=0.f;
    #pragma unroll
    for(int c=0;c<16;c++){ a += s_xp[(1+n)*16+c]*uu[c]; cch += s_xp[(17+n)*16+c]*uu[c]; }
    Bn[n]=a; Cn[n]=cch;
  }
  #pragma unroll
  for(int e=0;e<16;e++) dlv[e] = softplusf_(dbc0*s_dtw[e] + s_dtb[e]);

  size_t o = (size_t)gid*16;
  #pragma unroll
  for (int i=0;i<16;i+=4){
    *(float4*)(sz+o+i) = make_float4(szv[i],szv[i+1],szv[i+2],szv[i+3]);
    *(float4*)(u +o+i) = make_float4(uu[i],uu[i+1],uu[i+2],uu[i+3]);
    *(float4*)(dl+o+i) = make_float4(dlv[i],dlv[i+1],dlv[i+2],dlv[i+3]);
    *(float4*)(Bv+o+i) = make_float4(Bn[i],Bn[i+1],Bn[i+2],Bn[i+3]);
    *(float4*)(Cv+o+i) = make_float4(Cn[i],Cn[i+1],Cn[i+2],Cn[i+3]);
  }
}

// ---------------- selective scan ----------------
__global__ __launch_bounds__(64) void k_scan(const float* __restrict__ dl, const float* __restrict__ u,
                       const float* __restrict__ Bv, const float* __restrict__ Cv,
                       const float* __restrict__ A_log, const float* __restrict__ Dp,
                       float* __restrict__ y){
  int lane = threadIdx.x;
  int eg = blockIdx.x;      // 0..3
  int b  = blockIdx.y;
  int el = lane >> 4;
  int n  = lane & 15;
  int e  = eg*4 + el;
  float a_coef = -__expf(A_log[e*16 + n]);
  float De = Dp[e];
  const float* dp = dl + (size_t)b*L*16 + e;
  const float* up = u  + (size_t)b*L*16 + e;
  const float* bp = Bv + (size_t)b*L*16 + n;
  const float* cp = Cv + (size_t)b*L*16 + n;
  float* yp = y + (size_t)b*L*16 + e;
  float h = 0.f;
  #pragma unroll 4
  for (int t=0; t<L; t++){
    float d  = dp[(size_t)t*16];
    float uu = up[(size_t)t*16];
    float bb = bp[(size_t)t*16];
    float cc = cp[(size_t)t*16];
    float dA = __expf(d*a_coef);
    h = dA*h + d*bb*uu;
    float p = h*cc;
    p += __shfl_xor(p, 8, 64);
    p += __shfl_xor(p, 4, 64);
    p += __shfl_xor(p, 2, 64);
    p += __shfl_xor(p, 1, 64);
    if (n == 0) yp[(size_t)t*16] = p + De*uu;
  }
}

// ---------------- out_proj + residual ----------------
__global__ __launch_bounds__(256) void k_out(const float* __restrict__ y, const float* __restrict__ sz,
                      const float* __restrict__ out_w, // 8x16
                      float* __restrict__ f){
  __shared__ float s_ow[128];
  int tid=threadIdx.x;
  if (tid<128) s_ow[tid]=out_w[tid];
  __syncthreads();
  int gid = blockIdx.x*256 + tid;
  float yz[16];
  const float* yp = y + (size_t)gid*16;
  const float* zp = sz + (size_t)gid*16;
  #pragma unroll
  for(int e=0;e<16;e++) yz[e] = yp[e]*zp[e];
  float* fp = f + (size_t)gid*8;
  #pragma unroll
  for(int d=0;d<8;d++){
    float a=fp[d];
    #pragma unroll
    for(int e=0;e<16;e++) a += s_ow[d*16+e]*yz[e];
    fp[d]=a;
  }
}

// ---------------- fused head: c1 -> c2 -> c3 -> relu(h1+r) -> pooled sums ----------------
#define T_TILE 64
__global__ __launch_bounds__(256) void k_head(const float* __restrict__ f,
   const float* __restrict__ c1w, const float* __restrict__ c1b,
   const float* __restrict__ c2w, const float* __restrict__ c2b,
   const float* __restrict__ c3w, const float* __restrict__ c3b,
   float* __restrict__ pooled){
  __shared__ float h1s[64][72];
  __shared__ float h2s[64][68];
  __shared__ float sred[256];
  int tid = threadIdx.x;
  int b   = blockIdx.y;
  int t0  = blockIdx.x * T_TILE;

  // phase A: h1 cols 0..71  (t = t0-2+col)
  for (int task = tid; task < 64*72; task += 256){
    int c = task & 63, col = task >> 6;
    int t = t0 - 2 + col;
    float v = 0.f;
    if (t >= 0 && t < L){
      float a = c1b[c];
      #pragma unroll
      for (int k=0;k<3;k++){
        int tt = t + k - 1;
        if (tt < 0 || tt >= L) continue;
        const float* fr = f + ((size_t)b*L + tt)*8;
        #pragma unroll
        for (int d=0; d<8; d++) a += c1w[c*24 + d*3 + k] * fr[d];
      }
      v = fmaxf(a, 0.f);
    }
    h1s[c][col] = v;
  }
  __syncthreads();

  // phase B: h2 cols 0..67 (t = t0-1+col), col j uses h1s[:, j..j+2]
  for (int task = tid; task < 64*17; task += 256){
    int c = task & 63, q = task >> 6;
    int j0 = q*4;
    float acc[4] = {0.f,0.f,0.f,0.f};
    const float* w = c2w + c*192;
    for (int ci=0;ci<64;ci++){
      float hv0=h1s[ci][j0],   hv1=h1s[ci][j0+1], hv2=h1s[ci][j0+2],
            hv3=h1s[ci][j0+3], hv4=h1s[ci][j0+4], hv5=h1s[ci][j0+5];
      float w0=w[ci*3], w1=w[ci*3+1], w2=w[ci*3+2];
      acc[0] += w0*hv0 + w1*hv1 + w2*hv2;
      acc[1] += w0*hv1 + w1*hv2 + w2*hv3;
      acc[2] += w0*hv2 + w1*hv3 + w2*hv4;
      acc[3] += w0*hv3 + w1*hv4 + w2*hv5;
    }
    float bb = c2b[c];
    #pragma unroll
    for (int j=0;j<4;j++){
      int t = t0 - 1 + j0 + j;
      float av = acc[j] + bb;
      h2s[c][j0+j] = (t>=0 && t<L) ? fmaxf(av,0.f) : 0.f;
    }
  }
  __syncthreads();

  // phase C: r cols (t = t0+j0+j), uses h2s[:, j0+j .. j0+j+2], h1 at col j0+j+2
  float partial = 0.f;
  for (int task = tid; task < 64*16; task += 256){
    int c = task & 63, q = task >> 6;
    int j0 = q*4;
    float acc[4] = {0.f,0.f,0.f,0.f};
    const float* w = c3w + c*192;
    for (int ci=0;ci<64;ci++){
      float hv0=h2s[ci][j0],   hv1=h2s[ci][j0+1], hv2=h2s[ci][j0+2],
            hv3=h2s[ci][j0+3], hv4=h2s[ci][j0+4], hv5=h2s[ci][j0+5];
      float w0=w[ci*3], w1=w[ci*3+1], w2=w[ci*3+2];
      acc[0] += w0*hv0 + w1*hv1 + w2*hv2;
      acc[1] += w0*hv1 + w1*hv2 + w2*hv3;
      acc[2] += w0*hv2 + w1*hv3 + w2*hv4;
      acc[3] += w0*hv3 + w1*hv4 + w2*hv5;
    }
    float bb = c3b[c];
    #pragma unroll
    for (int j=0;j<4;j++){
      int t = t0 + j0 + j;
      if (t < L){
        float hr = fmaxf(h1s[c][j0+j+2] + acc[j] + bb, 0.f);
        partial += hr;
      }
    }
  }
  sred[tid] = partial;
  __syncthreads();
  if (tid < 64){
    float s = sred[tid] + sred[tid+64] + sred[tid+128] + sred[tid+192];
    atomicAdd(&pooled[b*64 + tid], s);
  }
}

// ---------------- final FC ----------------
__global__ void k_fc(const float* __restrict__ pooled, const float* __restrict__ fcw,
                     const float* __restrict__ fcb, float* __restrict__ out){
  int gid = blockIdx.x*256 + threadIdx.x;
  if (gid >= B*NC) return;
  int b = gid / NC, j = gid % NC;
  const float* p = pooled + b*64;
  const float* w = fcw + j*64;
  float a = 0.f;
  #pragma unroll
  for (int c=0;c<64;c++) a += p[c]*w[c];
  out[gid] = a*(1.f/(float)L) + fcb[j];
}

extern "C" void kernel_launch(void* const* d_in, const int* in_sizes, int n_in,
                              void* d_out, int out_size, void* d_ws, size_t ws_size,
                              hipStream_t stream){
  const float* x      = (const float*)d_in[0];
  const int*   idx    = (const int*)  d_in[1];
  const float* embed  = (const float*)d_in[2];
  const float* norm_w = (const float*)d_in[3];
  const float* in_proj= (const float*)d_in[4];
  const float* conv_w = (const float*)d_in[5];
  const float* conv_b = (const float*)d_in[6];
  const float* x_proj = (const float*)d_in[7];
  const float* dt_w   = (const float*)d_in[8];
  const float* dt_b   = (const float*)d_in[9];
  const float* A_log  = (const float*)d_in[10];
  const float* Dp     = (const float*)d_in[11];
  const float* out_w  = (const float*)d_in[12];
  const float* c1w    = (const float*)d_in[13];
  const float* c1b    = (const float*)d_in[14];
  const float* c2w    = (const float*)d_in[15];
  const float* c2b    = (const float*)d_in[16];
  const float* c3w    = (const float*)d_in[17];
  const float* c3b    = (const float*)d_in[18];
  const float* fcw    = (const float*)d_in[19];
  const float* fcb    = (const float*)d_in[20];
  float* out = (float*)d_out;

  float* ws = (float*)d_ws;
  float* f      = ws;              // B*L*8  = 5,120,000
  float* sz     = f  + 5120000;    // B*L*16 = 10,240,000
  float* u      = sz + 10240000;
  float* dl     = u  + 10240000;
  float* Bv     = dl + 10240000;
  float* Cv     = Bv + 10240000;
  float* y      = Cv + 10240000;
  float* pooled = y  + 10240000;   // B*64

  k_embed<<<2500,256,0,stream>>>(x, idx, embed, f);
  for (int l=0;l<NL;l++){
    k_pre<<<2500,256,0,stream>>>(f, norm_w + l*8, in_proj + l*256, conv_w + l*48,
         conv_b + l*16, x_proj + l*528, dt_w + l*16, dt_b + l*16, sz, u, dl, Bv, Cv);
    k_scan<<<dim3(4,B),64,0,stream>>>(dl, u, Bv, Cv, A_log + l*256, Dp + l*16, y);
    k_out<<<2500,256,0,stream>>>(y, sz, out_w + l*128, f);
  }
  hipMemsetAsync(pooled, 0, B*64*sizeof(float), stream);
  k_head<<<dim3(79,B),256,0,stream>>>(f, c1w, c1b, c2w, c2b, c3w, c3b, pooled);
  k_fc<<<(B*NC+255)/256,256,0,stream>>>(pooled, fcw, fcb, out);
}

// Round 4
// 2402.028 us; speedup vs baseline: 4.8004x; 4.8004x over previous
//
#include <hip/hip_runtime.h>
#include <math.h>

#define B 128
#define L 5000
#define DM 8
#define NL 4
#define DS 16
#define DI 16
#define HID 64
#define NC 230
#define NCH 20
#define LC 250
#define T_TILE 62

__device__ __forceinline__ float sigmoidf_(float x){ return 1.f/(1.f+__expf(-x)); }
__device__ __forceinline__ float siluf_(float x){ return x*sigmoidf_(x); }
__device__ __forceinline__ float softplusf_(float x){ return fmaxf(x,0.f) + log1pf(__expf(-fabsf(x))); }

// ---------------- f = embed[idx] * x ----------------
__global__ void k_embed(const float* __restrict__ x, const int* __restrict__ idx,
                        const float* __restrict__ embed, float* __restrict__ f){
  int gid = blockIdx.x*256 + threadIdx.x; // b*L + t
  if (gid >= B*L) return;
  int t = gid % L;
  float xv = x[gid];
  const float* er = embed + (size_t)idx[t]*DM;
  float4 e0 = *(const float4*)(er);
  float4 e1 = *(const float4*)(er+4);
  float4 o0 = make_float4(e0.x*xv, e0.y*xv, e0.z*xv, e0.w*xv);
  float4 o1 = make_float4(e1.x*xv, e1.y*xv, e1.z*xv, e1.w*xv);
  *(float4*)(f + (size_t)gid*8)   = o0;
  *(float4*)(f + (size_t)gid*8+4) = o1;
}

// ---------------- per-layer: rmsnorm + in_proj + conv + silu + x_proj + dt ----------------
__global__ __launch_bounds__(256) void k_pre(const float* __restrict__ f,
                      const float* __restrict__ norm_w,   // 8
                      const float* __restrict__ in_proj,  // 32x8
                      const float* __restrict__ conv_w,   // 16x3
                      const float* __restrict__ conv_b,   // 16
                      const float* __restrict__ x_proj,   // 33x16
                      const float* __restrict__ dt_w,     // 16
                      const float* __restrict__ dt_b,     // 16
                      float* __restrict__ sz, float* __restrict__ u,
                      float* __restrict__ dl, float* __restrict__ Bv, float* __restrict__ Cv){
  __shared__ float s_nw[8], s_ip[256], s_cw[48], s_cb[16], s_xp[528], s_dtw[16], s_dtb[16];
  int tid = threadIdx.x;
  if (tid < 8) s_nw[tid] = norm_w[tid];
  s_ip[tid] = in_proj[tid];
  if (tid < 48) s_cw[tid] = conv_w[tid];
  if (tid < 16){ s_cb[tid]=conv_b[tid]; s_dtw[tid]=dt_w[tid]; s_dtb[tid]=dt_b[tid]; }
  for (int i = tid; i < 528; i += 256) s_xp[i] = x_proj[i];
  __syncthreads();

  int gid = blockIdx.x*256 + tid;
  int t = gid % L;

  float xc3[3][16];
  float xn[8];
  #pragma unroll
  for (int j=0;j<3;j++){
    int tau = t-2+j;
    if (tau < 0){
      #pragma unroll
      for(int c=0;c<16;c++) xc3[j][c]=0.f;
      continue;
    }
    const float* fr = f + (size_t)(gid + (j-2))*8;
    float fv[8]; float ss=0.f;
    #pragma unroll
    for(int d=0;d<8;d++){ fv[d]=fr[d]; ss += fv[d]*fv[d]; }
    float r = rsqrtf(ss*(1.f/8.f) + 1e-5f);
    #pragma unroll
    for(int d=0;d<8;d++) xn[d] = fv[d]*r*s_nw[d];
    #pragma unroll
    for(int c=0;c<16;c++){
      float a=0.f;
      #pragma unroll
      for(int d=0;d<8;d++) a += s_ip[c*8+d]*xn[d];
      xc3[j][c]=a;
    }
  }
  float uu[16];
  #pragma unroll
  for(int c=0;c<16;c++){
    float a = s_cb[c] + s_cw[c*3+0]*xc3[0][c] + s_cw[c*3+1]*xc3[1][c] + s_cw[c*3+2]*xc3[2][c];
    uu[c] = siluf_(a);
  }
  float szv[16];
  #pragma unroll
  for(int c=0;c<16;c++){
    float a=0.f;
    #pragma unroll
    for(int d=0;d<8;d++) a += s_ip[(16+c)*8+d]*xn[d];
    szv[c] = siluf_(a);
  }
  float dbc0=0.f;
  #pragma unroll
  for(int c=0;c<16;c++) dbc0 += s_xp[c]*uu[c];
  float dlv[16], Bn[16], Cn[16];
  #pragma unroll
  for(int n=0;n<16;n++){
    float a=0.f, cch=0.f;
    #pragma unroll
    for(int c=0;c<16;c++){ a += s_xp[(1+n)*16+c]*uu[c]; cch += s_xp[(17+n)*16+c]*uu[c]; }
    Bn[n]=a; Cn[n]=cch;
  }
  #pragma unroll
  for(int e=0;e<16;e++) dlv[e] = softplusf_(dbc0*s_dtw[e] + s_dtb[e]);

  size_t o = (size_t)gid*16;
  #pragma unroll
  for (int i=0;i<16;i+=4){
    *(float4*)(sz+o+i) = make_float4(szv[i],szv[i+1],szv[i+2],szv[i+3]);
    *(float4*)(u +o+i) = make_float4(uu[i],uu[i+1],uu[i+2],uu[i+3]);
    *(float4*)(dl+o+i) = make_float4(dlv[i],dlv[i+1],dlv[i+2],dlv[i+3]);
    *(float4*)(Bv+o+i) = make_float4(Bn[i],Bn[i+1],Bn[i+2],Bn[i+3]);
    *(float4*)(Cv+o+i) = make_float4(Cn[i],Cn[i+1],Cn[i+2],Cn[i+3]);
  }
}

// ---------------- chunked selective scan ----------------
// pass 1: per-chunk zero-init scan end S and transition P = exp(a * sum(delta))
__global__ __launch_bounds__(256) void k_scan_p1(const float* __restrict__ dl, const float* __restrict__ u,
    const float* __restrict__ Bv, const float* __restrict__ A_log,
    float* __restrict__ Sc, float* __restrict__ Pc){
  int tid = threadIdx.x;
  int ch = blockIdx.x, b = blockIdx.y;
  int e = tid >> 4, n = tid & 15;
  float a = -__expf(A_log[e*16+n]);
  size_t base = ((size_t)b*L + ch*LC)*16;
  const float* dp = dl + base + e;
  const float* up = u  + base + e;
  const float* bp = Bv + base + n;
  float h = 0.f, dsum = 0.f;
  #pragma unroll 4
  for (int t=0;t<LC;t++){
    float d  = dp[t*16];
    float uu = up[t*16];
    float bb = bp[t*16];
    float dA = __expf(d*a);
    h = dA*h + d*bb*uu;
    dsum += d;
  }
  size_t o = ((size_t)b*NCH + ch)*256 + tid;
  Sc[o] = h;
  Pc[o] = __expf(a*dsum);
}

// pass 2: serial scan over chunks -> h0 per chunk
__global__ __launch_bounds__(256) void k_scan_p2(const float* __restrict__ Sc, const float* __restrict__ Pc,
    float* __restrict__ h0){
  int tid = threadIdx.x;
  int b = blockIdx.x;
  float h = 0.f;
  for (int ch=0; ch<NCH; ch++){
    size_t o = ((size_t)b*NCH + ch)*256 + tid;
    h0[o] = h;
    h = Pc[o]*h + Sc[o];
  }
}

// pass 3: exact within-chunk recurrence from h0, emit y.
// NOTE: y aliases dl (in-place). Safe: the store to y[base+t*16+e] is data-
// dependent on the load of dl[base+t*16+e] (same address, same iteration),
// and all other loads target different addresses.
__global__ __launch_bounds__(256) void k_scan_p3(const float* __restrict__ dl, const float* __restrict__ u,
    const float* __restrict__ Bv, const float* __restrict__ Cv, const float* __restrict__ h0,
    const float* __restrict__ A_log, const float* __restrict__ Dp, float* __restrict__ y){
  int tid = threadIdx.x;
  int ch = blockIdx.x, b = blockIdx.y;
  int e = tid >> 4, n = tid & 15;
  float a = -__expf(A_log[e*16+n]);
  float De = Dp[e];
  size_t base = ((size_t)b*L + ch*LC)*16;
  const float* dp = dl + base + e;
  const float* up = u  + base + e;
  const float* bp = Bv + base + n;
  const float* cp = Cv + base + n;
  float* yp = y + base + e;
  float h = h0[((size_t)b*NCH + ch)*256 + tid];
  #pragma unroll 4
  for (int t=0;t<LC;t++){
    float d  = dp[t*16];
    float uu = up[t*16];
    float bb = bp[t*16];
    float cc = cp[t*16];
    float dA = __expf(d*a);
    h = dA*h + d*bb*uu;
    float p = h*cc;
    p += __shfl_xor(p, 1, 64);
    p += __shfl_xor(p, 2, 64);
    p += __shfl_xor(p, 4, 64);
    p += __shfl_xor(p, 8, 64);
    if (n == 0) yp[t*16] = p + De*uu;
  }
}

// ---------------- out_proj + residual ----------------
__global__ __launch_bounds__(256) void k_out(const float* __restrict__ y, const float* __restrict__ sz,
                      const float* __restrict__ out_w, // 8x16
                      float* __restrict__ f){
  __shared__ float s_ow[128];
  int tid=threadIdx.x;
  if (tid<128) s_ow[tid]=out_w[tid];
  __syncthreads();
  int gid = blockIdx.x*256 + tid;
  float yz[16];
  const float* yp = y + (size_t)gid*16;
  const float* zp = sz + (size_t)gid*16;
  #pragma unroll
  for(int e=0;e<16;e++) yz[e] = yp[e]*zp[e];
  float* fp = f + (size_t)gid*8;
  #pragma unroll
  for(int d=0;d<8;d++){
    float a=fp[d];
    #pragma unroll
    for(int e=0;e<16;e++) a += s_ow[d*16+e]*yz[e];
    fp[d]=a;
  }
}

// ---------------- transpose head weights: wt[r][c] = w[c][r] ----------------
__global__ void k_wt(const float* __restrict__ c1w, const float* __restrict__ c2w,
                     const float* __restrict__ c3w, float* __restrict__ wt1,
                     float* __restrict__ wt2, float* __restrict__ wt3){
  int idx = blockIdx.x*256 + threadIdx.x;
  if (idx < 1536){
    int r = idx >> 6, c = idx & 63;
    wt1[idx] = c1w[c*24 + r];
  } else if (idx < 1536 + 12288){
    int i = idx - 1536;
    int r = i >> 6, c = i & 63;
    wt2[i] = c2w[c*192 + r];
  } else if (idx < 1536 + 24576){
    int i = idx - 1536 - 12288;
    int r = i >> 6, c = i & 63;
    wt3[i] = c3w[c*192 + r];
  }
}

// ---------------- fused head: lanes = time cols, wave = 16 channels ----------------
__global__ __launch_bounds__(256) void k_head(const float* __restrict__ f,
   const float* __restrict__ wt1, const float* __restrict__ c1b,
   const float* __restrict__ wt2, const float* __restrict__ c2b,
   const float* __restrict__ wt3, const float* __restrict__ c3b,
   float* __restrict__ pooled){
  __shared__ float fs[8][68];
  __shared__ float h1s[64][66];
  __shared__ float h2s[64][66];
  __shared__ float sred[64][65];
  __shared__ float sredp[64][4];
  int tid  = threadIdx.x;
  int b    = blockIdx.y;
  int t0   = blockIdx.x * T_TILE;
  int lane = tid & 63;
  int cb   = __builtin_amdgcn_readfirstlane((tid >> 6) << 4);

  // stage f rows t0-3 .. t0+64 (68 rows x 8)
  for (int task = tid; task < 544; task += 256){
    int d = task & 7, r = task >> 3;
    int t = t0 - 3 + r;
    fs[d][r] = (t >= 0 && t < L) ? f[((size_t)b*L + t)*8 + d] : 0.f;
  }
  __syncthreads();

  // phase A: h1 cols 0..65 (t = t0-2+col)
  #pragma unroll
  for (int rep = 0; rep < 2; rep++){
    int col = lane + rep*64;
    if (col < 66){
      int t = t0 - 2 + col;
      bool valid = (t >= 0 && t < L);
      float acc[16];
      #pragma unroll
      for (int cc=0; cc<16; cc++) acc[cc] = c1b[cb+cc];
      #pragma unroll
      for (int k=0;k<3;k++){
        #pragma unroll
        for (int d=0; d<8; d++){
          float fv = fs[d][col + k];
          const float* wr = wt1 + (d*3+k)*64 + cb;
          #pragma unroll
          for (int cc=0; cc<16; cc++) acc[cc] += wr[cc]*fv;
        }
      }
      #pragma unroll
      for (int cc=0; cc<16; cc++)
        h1s[cb+cc][col] = valid ? fmaxf(acc[cc],0.f) : 0.f;
    }
  }
  __syncthreads();

  // phase B: h2 cols 0..63 (t = t0-1+col), window h1 cols col..col+2
  {
    int col = lane;
    int t = t0 - 1 + col;
    bool valid = (t >= 0 && t < L);
    float acc[16];
    #pragma unroll
    for (int cc=0;cc<16;cc++) acc[cc] = c2b[cb+cc];
    for (int ci=0; ci<64; ci++){
      float hv0 = h1s[ci][col];
      float hv1 = h1s[ci][col+1];
      float hv2 = h1s[ci][col+2];
      const float* wr = wt2 + ci*192 + cb;
      #pragma unroll
      for (int cc=0; cc<16; cc++)
        acc[cc] += wr[cc]*hv0 + wr[64+cc]*hv1 + wr[128+cc]*hv2;
    }
    #pragma unroll
    for (int cc=0; cc<16; cc++)
      h2s[cb+cc][col] = valid ? fmaxf(acc[cc],0.f) : 0.f;
    if (lane < 2){
      #pragma unroll
      for (int cc=0; cc<16; cc++) h2s[cb+cc][64+lane] = 0.f;
    }
  }
  __syncthreads();

  // phase C: outputs t = t0+col for col<62; window h2 cols col..col+2; residual h1 col+2
  {
    int col = lane;
    int t = t0 + col;
    bool valid = (col < T_TILE) && (t < L);
    float acc[16];
    #pragma unroll
    for (int cc=0;cc<16;cc++) acc[cc] = c3b[cb+cc];
    for (int ci=0; ci<64; ci++){
      float hv0 = h2s[ci][col];
      float hv1 = h2s[ci][col+1];
      float hv2 = h2s[ci][col+2];
      const float* wr = wt3 + ci*192 + cb;
      #pragma unroll
      for (int cc=0; cc<16; cc++)
        acc[cc] += wr[cc]*hv0 + wr[64+cc]*hv1 + wr[128+cc]*hv2;
    }
    #pragma unroll
    for (int cc=0; cc<16; cc++){
      float hr = fmaxf(h1s[cb+cc][col+2] + acc[cc], 0.f);
      sred[cb+cc][col] = valid ? hr : 0.f;
    }
  }
  __syncthreads();

  // reduce sred over cols -> pooled
  {
    int c = tid & 63, q = tid >> 6;
    float s = 0.f;
    #pragma unroll
    for (int i=0;i<16;i++) s += sred[c][q*16+i];
    sredp[c][q] = s;
  }
  __syncthreads();
  if (tid < 64){
    float s = sredp[tid][0]+sredp[tid][1]+sredp[tid][2]+sredp[tid][3];
    atomicAdd(&pooled[b*64 + tid], s);
  }
}

// ---------------- final FC ----------------
__global__ void k_fc(const float* __restrict__ pooled, const float* __restrict__ fcw,
                     const float* __restrict__ fcb, float* __restrict__ out){
  int gid = blockIdx.x*256 + threadIdx.x;
  if (gid >= B*NC) return;
  int b = gid / NC, j = gid % NC;
  const float* p = pooled + b*64;
  const float* w = fcw + j*64;
  float a = 0.f;
  #pragma unroll
  for (int c=0;c<64;c++) a += p[c]*w[c];
  out[gid] = a*(1.f/(float)L) + fcb[j];
}

extern "C" void kernel_launch(void* const* d_in, const int* in_sizes, int n_in,
                              void* d_out, int out_size, void* d_ws, size_t ws_size,
                              hipStream_t stream){
  const float* x      = (const float*)d_in[0];
  const int*   idx    = (const int*)  d_in[1];
  const float* embed  = (const float*)d_in[2];
  const float* norm_w = (const float*)d_in[3];
  const float* in_proj= (const float*)d_in[4];
  const float* conv_w = (const float*)d_in[5];
  const float* conv_b = (const float*)d_in[6];
  const float* x_proj = (const float*)d_in[7];
  const float* dt_w   = (const float*)d_in[8];
  const float* dt_b   = (const float*)d_in[9];
  const float* A_log  = (const float*)d_in[10];
  const float* Dp     = (const float*)d_in[11];
  const float* out_w  = (const float*)d_in[12];
  const float* c1w    = (const float*)d_in[13];
  const float* c1b    = (const float*)d_in[14];
  const float* c2w    = (const float*)d_in[15];
  const float* c2b    = (const float*)d_in[16];
  const float* c3w    = (const float*)d_in[17];
  const float* c3b    = (const float*)d_in[18];
  const float* fcw    = (const float*)d_in[19];
  const float* fcb    = (const float*)d_in[20];
  float* out = (float*)d_out;

  // workspace layout: 58,320,384 floats = 233.3 MB (round-1's 266 MB worked;
  // round-2's 269 MB crashed -> stay well under)
  float* ws = (float*)d_ws;
  float* f      = ws;               // 5,120,000
  float* sz     = f  + 5120000;     // 10,240,000
  float* u      = sz + 10240000;    // 10,240,000
  float* dl     = u  + 10240000;    // 10,240,000  (y aliases dl)
  float* Bv     = dl + 10240000;    // 10,240,000
  float* Cv     = Bv + 10240000;    // 10,240,000
  float* Sc     = Cv + 10240000;    // 655,360
  float* Pc     = Sc + 655360;      // 655,360
  float* h0     = Pc + 655360;      // 655,360
  float* pooled = h0 + 655360;      // 8,192
  float* wt1    = pooled + 8192;    // 1,536
  float* wt2    = wt1 + 1536;       // 12,288
  float* wt3    = wt2 + 12288;      // 12,288
  float* y      = dl;               // in-place

  k_wt<<<102,256,0,stream>>>(c1w, c2w, c3w, wt1, wt2, wt3);
  k_embed<<<2500,256,0,stream>>>(x, idx, embed, f);
  for (int l=0;l<NL;l++){
    k_pre<<<2500,256,0,stream>>>(f, norm_w + l*8, in_proj + l*256, conv_w + l*48,
         conv_b + l*16, x_proj + l*528, dt_w + l*16, dt_b + l*16, sz, u, dl, Bv, Cv);
    k_scan_p1<<<dim3(NCH,B),256,0,stream>>>(dl, u, Bv, A_log + l*256, Sc, Pc);
    k_scan_p2<<<B,256,0,stream>>>(Sc, Pc, h0);
    k_scan_p3<<<dim3(NCH,B),256,0,stream>>>(dl, u, Bv, Cv, h0, A_log + l*256, Dp + l*16, y);
    k_out<<<2500,256,0,stream>>>(y, sz, out_w + l*128, f);
  }
  hipMemsetAsync(pooled, 0, B*64*sizeof(float), stream);
  k_head<<<dim3(81,B),256,0,stream>>>(f, wt1, c1b, wt2, c2b, wt3, c3b, pooled);
  k_fc<<<(B*NC+255)/256,256,0,stream>>>(pooled, fcw, fcb, out);
}

// Round 5
// 2166.208 us; speedup vs baseline: 5.3229x; 1.1089x over previous
//
#include <hip/hip_runtime.h>
#include <math.h>

#define B 128
#define L 5000
#define DM 8
#define NL 4
#define DS 16
#define DI 16
#define HID 64
#define NC 230
#define NCH 20
#define LC 250
#define HT 64   // head outputs per block

typedef __attribute__((ext_vector_type(8))) short bf16x8;
typedef __attribute__((ext_vector_type(4))) short short4v;
typedef __attribute__((ext_vector_type(4))) float f32x4;

__device__ __forceinline__ float sigmoidf_(float x){ return 1.f/(1.f+__expf(-x)); }
__device__ __forceinline__ float siluf_(float x){ return x*sigmoidf_(x); }
__device__ __forceinline__ float softplusf_(float x){ return fmaxf(x,0.f) + log1pf(__expf(-fabsf(x))); }
__device__ __forceinline__ short bfc_(float x){
  union { float f; unsigned u; } v; v.f = x;
  unsigned r = v.u + 0x7fffu + ((v.u >> 16) & 1u);
  return (short)(r >> 16);
}
__device__ __forceinline__ float b2f_(short s){
  union { unsigned u; float f; } v; v.u = ((unsigned)(unsigned short)s) << 16;
  return v.f;
}

// ---------------- f = embed[idx] * x ----------------
__global__ void k_embed(const float* __restrict__ x, const int* __restrict__ idx,
                        const float* __restrict__ embed, float* __restrict__ f){
  int gid = blockIdx.x*256 + threadIdx.x; // b*L + t
  if (gid >= B*L) return;
  int t = gid % L;
  float xv = x[gid];
  const float* er = embed + (size_t)idx[t]*DM;
  float4 e0 = *(const float4*)(er);
  float4 e1 = *(const float4*)(er+4);
  float4 o0 = make_float4(e0.x*xv, e0.y*xv, e0.z*xv, e0.w*xv);
  float4 o1 = make_float4(e1.x*xv, e1.y*xv, e1.z*xv, e1.w*xv);
  *(float4*)(f + (size_t)gid*8)   = o0;
  *(float4*)(f + (size_t)gid*8+4) = o1;
}

// ---------------- per-layer: rmsnorm + in_proj + conv + silu + x_proj + dt ----------------
__global__ __launch_bounds__(256) void k_pre(const float* __restrict__ f,
                      const float* __restrict__ norm_w,   // 8
                      const float* __restrict__ in_proj,  // 32x8
                      const float* __restrict__ conv_w,   // 16x3
                      const float* __restrict__ conv_b,   // 16
                      const float* __restrict__ x_proj,   // 33x16
                      const float* __restrict__ dt_w,     // 16
                      const float* __restrict__ dt_b,     // 16
                      float* __restrict__ sz, float* __restrict__ u,
                      float* __restrict__ dl, float* __restrict__ Bv, float* __restrict__ Cv){
  __shared__ float s_nw[8], s_ip[256], s_cw[48], s_cb[16], s_xp[528], s_dtw[16], s_dtb[16];
  int tid = threadIdx.x;
  if (tid < 8) s_nw[tid] = norm_w[tid];
  s_ip[tid] = in_proj[tid];
  if (tid < 48) s_cw[tid] = conv_w[tid];
  if (tid < 16){ s_cb[tid]=conv_b[tid]; s_dtw[tid]=dt_w[tid]; s_dtb[tid]=dt_b[tid]; }
  for (int i = tid; i < 528; i += 256) s_xp[i] = x_proj[i];
  __syncthreads();

  int gid = blockIdx.x*256 + tid;
  int t = gid % L;

  float xc3[3][16];
  float xn[8];
  #pragma unroll
  for (int j=0;j<3;j++){
    int tau = t-2+j;
    if (tau < 0){
      #pragma unroll
      for(int c=0;c<16;c++) xc3[j][c]=0.f;
      continue;
    }
    const float* fr = f + (size_t)(gid + (j-2))*8;
    float fv[8]; float ss=0.f;
    #pragma unroll
    for(int d=0;d<8;d++){ fv[d]=fr[d]; ss += fv[d]*fv[d]; }
    float r = rsqrtf(ss*(1.f/8.f) + 1e-5f);
    #pragma unroll
    for(int d=0;d<8;d++) xn[d] = fv[d]*r*s_nw[d];
    #pragma unroll
    for(int c=0;c<16;c++){
      float a=0.f;
      #pragma unroll
      for(int d=0;d<8;d++) a += s_ip[c*8+d]*xn[d];
      xc3[j][c]=a;
    }
  }
  float uu[16];
  #pragma unroll
  for(int c=0;c<16;c++){
    float a = s_cb[c] + s_cw[c*3+0]*xc3[0][c] + s_cw[c*3+1]*xc3[1][c] + s_cw[c*3+2]*xc3[2][c];
    uu[c] = siluf_(a);
  }
  float szv[16];
  #pragma unroll
  for(int c=0;c<16;c++){
    float a=0.f;
    #pragma unroll
    for(int d=0;d<8;d++) a += s_ip[(16+c)*8+d]*xn[d];
    szv[c] = siluf_(a);
  }
  float dbc0=0.f;
  #pragma unroll
  for(int c=0;c<16;c++) dbc0 += s_xp[c]*uu[c];
  float dlv[16], Bn[16], Cn[16];
  #pragma unroll
  for(int n=0;n<16;n++){
    float a=0.f, cch=0.f;
    #pragma unroll
    for(int c=0;c<16;c++){ a += s_xp[(1+n)*16+c]*uu[c]; cch += s_xp[(17+n)*16+c]*uu[c]; }
    Bn[n]=a; Cn[n]=cch;
  }
  #pragma unroll
  for(int e=0;e<16;e++) dlv[e] = softplusf_(dbc0*s_dtw[e] + s_dtb[e]);

  size_t o = (size_t)gid*16;
  #pragma unroll
  for (int i=0;i<16;i+=4){
    *(float4*)(sz+o+i) = make_float4(szv[i],szv[i+1],szv[i+2],szv[i+3]);
    *(float4*)(u +o+i) = make_float4(uu[i],uu[i+1],uu[i+2],uu[i+3]);
    *(float4*)(dl+o+i) = make_float4(dlv[i],dlv[i+1],dlv[i+2],dlv[i+3]);
    *(float4*)(Bv+o+i) = make_float4(Bn[i],Bn[i+1],Bn[i+2],Bn[i+3]);
    *(float4*)(Cv+o+i) = make_float4(Cn[i],Cn[i+1],Cn[i+2],Cn[i+3]);
  }
}

// ---------------- chunked selective scan ----------------
__global__ __launch_bounds__(256) void k_scan_p1(const float* __restrict__ dl, const float* __restrict__ u,
    const float* __restrict__ Bv, const float* __restrict__ A_log,
    float* __restrict__ Sc, float* __restrict__ Pc){
  int tid = threadIdx.x;
  int ch = blockIdx.x, b = blockIdx.y;
  int e = tid >> 4, n = tid & 15;
  float a = -__expf(A_log[e*16+n]);
  size_t base = ((size_t)b*L + ch*LC)*16;
  const float* dp = dl + base + e;
  const float* up = u  + base + e;
  const float* bp = Bv + base + n;
  float h = 0.f, dsum = 0.f;
  #pragma unroll 4
  for (int t=0;t<LC;t++){
    float d  = dp[t*16];
    float uu = up[t*16];
    float bb = bp[t*16];
    float dA = __expf(d*a);
    h = dA*h + d*bb*uu;
    dsum += d;
  }
  size_t o = ((size_t)b*NCH + ch)*256 + tid;
  Sc[o] = h;
  Pc[o] = __expf(a*dsum);
}

__global__ __launch_bounds__(256) void k_scan_p2(const float* __restrict__ Sc, const float* __restrict__ Pc,
    float* __restrict__ h0){
  int tid = threadIdx.x;
  int b = blockIdx.x;
  float h = 0.f;
  for (int ch=0; ch<NCH; ch++){
    size_t o = ((size_t)b*NCH + ch)*256 + tid;
    h0[o] = h;
    h = Pc[o]*h + Sc[o];
  }
}

// pass 3 fused with out_proj: scan 25-step subtiles into LDS, then apply
// f += (y .* silu(z)) @ out_w^T for those 25 t's. No y traffic to HBM.
__global__ __launch_bounds__(256) void k_scan_p3o(const float* __restrict__ dl, const float* __restrict__ u,
    const float* __restrict__ Bv, const float* __restrict__ Cv, const float* __restrict__ h0,
    const float* __restrict__ A_log, const float* __restrict__ Dp,
    const float* __restrict__ sz, const float* __restrict__ ow, float* __restrict__ f){
  __shared__ float s_ow[128];
  __shared__ float y_lds[25][16];
  __shared__ float sz_lds[25][16];
  int tid = threadIdx.x;
  int ch = blockIdx.x, b = blockIdx.y;
  int e = tid >> 4, n = tid & 15;
  if (tid < 128) s_ow[tid] = ow[tid];
  float a = -__expf(A_log[e*16+n]);
  float De = Dp[e];
  size_t base0 = ((size_t)b*L + ch*LC)*16;
  size_t fbase = ((size_t)b*L + ch*LC)*8;
  const float* dp = dl + base0 + e;
  const float* up = u  + base0 + e;
  const float* bp = Bv + base0 + n;
  const float* cp = Cv + base0 + n;
  const float* szp = sz + base0;
  float h = h0[((size_t)b*NCH + ch)*256 + tid];
  for (int tt=0; tt<LC; tt+=25){
    for (int i=tid; i<400; i+=256) sz_lds[i>>4][i&15] = szp[tt*16 + i];
    __syncthreads();
    #pragma unroll 5
    for (int tl=0; tl<25; tl++){
      int t = tt + tl;
      float d  = dp[t*16];
      float uu = up[t*16];
      float bb = bp[t*16];
      float cc = cp[t*16];
      float dA = __expf(d*a);
      h = dA*h + d*bb*uu;
      float p = h*cc;
      p += __shfl_xor(p, 1, 64);
      p += __shfl_xor(p, 2, 64);
      p += __shfl_xor(p, 4, 64);
      p += __shfl_xor(p, 8, 64);
      if (n == 0) y_lds[tl][e] = p + De*uu;
    }
    __syncthreads();
    if (tid < 200){
      int tl = tid >> 3, d = tid & 7;
      size_t fi = fbase + (size_t)(tt+tl)*8 + d;
      float acc = f[fi];
      #pragma unroll
      for (int e2=0;e2<16;e2++) acc += s_ow[d*16+e2]*y_lds[tl][e2]*sz_lds[tl][e2];
      f[fi] = acc;
    }
    __syncthreads();
  }
}

// ---------------- head weight prep: wt1 fp32 [d*3+k][c]; wt2b/wt3b bf16 [c][k*64+ci] ----------------
__global__ void k_wt(const float* __restrict__ c1w, const float* __restrict__ c2w,
                     const float* __restrict__ c3w, float* __restrict__ wt1,
                     short* __restrict__ wt2b, short* __restrict__ wt3b){
  int idx = blockIdx.x*256 + threadIdx.x;
  if (idx < 1536){
    int r = idx >> 6, c = idx & 63;
    wt1[idx] = c1w[c*24 + r];
  } else if (idx < 1536 + 12288){
    int i = idx - 1536;
    int c = i / 192, rem = i % 192;
    int k = rem >> 6, ci = rem & 63;
    wt2b[i] = bfc_(c2w[c*192 + ci*3 + k]);
  } else if (idx < 1536 + 24576){
    int i = idx - 1536 - 12288;
    int c = i / 192, rem = i % 192;
    int k = rem >> 6, ci = rem & 63;
    wt3b[i] = bfc_(c3w[c*192 + ci*3 + k]);
  }
}

// ---------------- fused head with MFMA for c2/c3 ----------------
// per block: (b, 64-wide t tile). c1 fp32 -> h1t bf16 LDS [time][ci] (stride 72),
// c2/c3 as bf16 MFMA GEMMs M=64,K=192. Pool summed via shfl + atomicAdd.
__global__ __launch_bounds__(256) void k_head(const float* __restrict__ f,
   const float* __restrict__ wt1, const float* __restrict__ c1b,
   const short* __restrict__ wt2b, const float* __restrict__ c2b,
   const short* __restrict__ wt3b, const float* __restrict__ c3b,
   float* __restrict__ pooled){
  __shared__ float fs[8][72];
  __shared__ float s_c1b[64];
  __shared__ short h1t[84*72];  // rows: h1 times t0-2..t0+65 (68 real, pad for N-overrun reads)
  __shared__ short h2t[66*72];  // rows: h2 times t0-1..t0+64 (66)
  int tid  = threadIdx.x;
  int b    = blockIdx.y;
  int t0   = blockIdx.x * HT;
  int lane = tid & 63;
  int w    = tid >> 6;
  int cb   = w*16;

  // stage f rows t0-3 .. t0+66 (70 rows x 8) and c1 bias
  for (int task = tid; task < 560; task += 256){
    int d = task & 7, r = task >> 3;
    int t = t0 - 3 + r;
    fs[d][r] = (t >= 0 && t < L) ? f[((size_t)b*L + t)*8 + d] : 0.f;
  }
  if (tid < 64) s_c1b[tid] = c1b[tid];
  __syncthreads();

  // phase A: c1 fp32 -> h1t bf16 (cols 0..67 ; t1 = t0-2+col)
  #pragma unroll
  for (int rep = 0; rep < 2; rep++){
    int col = lane + rep*64;
    if (col < 68){
      int t1 = t0 - 2 + col;
      bool valid = (t1 >= 0 && t1 < L);
      float acc[16];
      #pragma unroll
      for (int cc=0; cc<16; cc++) acc[cc] = s_c1b[cb+cc];
      #pragma unroll
      for (int k=0;k<3;k++){
        #pragma unroll
        for (int d=0; d<8; d++){
          float fv = fs[d][col + k];
          const float* wr = wt1 + (d*3+k)*64 + cb;
          #pragma unroll
          for (int cc=0; cc<16; cc++) acc[cc] += wr[cc]*fv;
        }
      }
      bf16x8 v0, v1;
      #pragma unroll
      for (int i=0;i<8;i++){
        v0[i] = bfc_(valid ? fmaxf(acc[i],0.f)   : 0.f);
        v1[i] = bfc_(valid ? fmaxf(acc[8+i],0.f) : 0.f);
      }
      *(bf16x8*)&h1t[col*72 + cb]     = v0;
      *(bf16x8*)&h1t[col*72 + cb + 8] = v1;
    }
  }
  __syncthreads();

  // c2: h2[c][tau] = relu(b2 + W2 x h1-windows), M=64(c) K=192 N=80(5x16, 66 real)
  {
    const short* wA = wt2b + (cb + (lane&15))*192 + ((lane>>4)*8);
    bf16x8 a2[6];
    #pragma unroll
    for (int s=0;s<6;s++) a2[s] = *(const bf16x8*)(wA + 32*s);
    f32x4 bias2 = *(const f32x4*)(c2b + cb + ((lane>>4)<<2));
    #pragma unroll
    for (int nt=0; nt<5; nt++){
      f32x4 acc = {0.f,0.f,0.f,0.f};
      #pragma unroll
      for (int s=0;s<6;s++){
        int k = s>>1, ci0 = (s&1)*32;
        int jr = nt*16 + (lane&15) + k;
        bf16x8 bfr = *(bf16x8*)&h1t[jr*72 + ci0 + ((lane>>4)*8)];
        acc = __builtin_amdgcn_mfma_f32_16x16x32_bf16(a2[s], bfr, acc, 0, 0, 0);
      }
      int tr = nt*16 + (lane&15);
      if (tr < 66){
        int tg = t0 - 1 + tr;
        bool v = (tg >= 0 && tg < L);
        short4v pk;
        #pragma unroll
        for (int reg=0;reg<4;reg++)
          pk[reg] = bfc_(v ? fmaxf(acc[reg] + bias2[reg], 0.f) : 0.f);
        *(short4v*)&h2t[tr*72 + cb + ((lane>>4)<<2)] = pk;
      }
    }
  }
  __syncthreads();

  // c3 + residual relu + pool: r[c][t], t = t0 + nt*16 + (lane&15)
  {
    const short* wA = wt3b + (cb + (lane&15))*192 + ((lane>>4)*8);
    bf16x8 a3[6];
    #pragma unroll
    for (int s=0;s<6;s++) a3[s] = *(const bf16x8*)(wA + 32*s);
    f32x4 bias3 = *(const f32x4*)(c3b + cb + ((lane>>4)<<2));
    int c0 = cb + ((lane>>4)<<2);
    float pool[4] = {0.f,0.f,0.f,0.f};
    #pragma unroll
    for (int nt=0; nt<4; nt++){
      f32x4 acc = {0.f,0.f,0.f,0.f};
      #pragma unroll
      for (int s=0;s<6;s++){
        int k = s>>1, ci0 = (s&1)*32;
        int jr = nt*16 + (lane&15) + k;   // h2t row (tau - (t0-1)) = tr + k
        bf16x8 bfr = *(bf16x8*)&h2t[jr*72 + ci0 + ((lane>>4)*8)];
        acc = __builtin_amdgcn_mfma_f32_16x16x32_bf16(a3[s], bfr, acc, 0, 0, 0);
      }
      int t = t0 + nt*16 + (lane&15);
      short4v hres = *(short4v*)&h1t[(nt*16 + (lane&15) + 2)*72 + c0];
      if (t < L){
        #pragma unroll
        for (int reg=0;reg<4;reg++)
          pool[reg] += fmaxf(b2f_(hres[reg]) + acc[reg] + bias3[reg], 0.f);
      }
    }
    #pragma unroll
    for (int m=1; m<16; m<<=1){
      #pragma unroll
      for (int reg=0;reg<4;reg++) pool[reg] += __shfl_xor(pool[reg], m, 64);
    }
    if ((lane & 15) == 0){
      #pragma unroll
      for (int reg=0;reg<4;reg++) atomicAdd(&pooled[b*64 + c0 + reg], pool[reg]);
    }
  }
}

// ---------------- final FC ----------------
__global__ void k_fc(const float* __restrict__ pooled, const float* __restrict__ fcw,
                     const float* __restrict__ fcb, float* __restrict__ out){
  int gid = blockIdx.x*256 + threadIdx.x;
  if (gid >= B*NC) return;
  int b = gid / NC, j = gid % NC;
  const float* p = pooled + b*64;
  const float* w = fcw + j*64;
  float a = 0.f;
  #pragma unroll
  for (int c=0;c<64;c++) a += p[c]*w[c];
  out[gid] = a*(1.f/(float)L) + fcb[j];
}

extern "C" void kernel_launch(void* const* d_in, const int* in_sizes, int n_in,
                              void* d_out, int out_size, void* d_ws, size_t ws_size,
                              hipStream_t stream){
  const float* x      = (const float*)d_in[0];
  const int*   idx    = (const int*)  d_in[1];
  const float* embed  = (const float*)d_in[2];
  const float* norm_w = (const float*)d_in[3];
  const float* in_proj= (const float*)d_in[4];
  const float* conv_w = (const float*)d_in[5];
  const float* conv_b = (const float*)d_in[6];
  const float* x_proj = (const float*)d_in[7];
  const float* dt_w   = (const float*)d_in[8];
  const float* dt_b   = (const float*)d_in[9];
  const float* A_log  = (const float*)d_in[10];
  const float* Dp     = (const float*)d_in[11];
  const float* out_w  = (const float*)d_in[12];
  const float* c1w    = (const float*)d_in[13];
  const float* c1b    = (const float*)d_in[14];
  const float* c2w    = (const float*)d_in[15];
  const float* c2b    = (const float*)d_in[16];
  const float* c3w    = (const float*)d_in[17];
  const float* c3b    = (const float*)d_in[18];
  const float* fcw    = (const float*)d_in[19];
  const float* fcb    = (const float*)d_in[20];
  float* out = (float*)d_out;

  // workspace: ~58.31M floats = 233 MB (266 MB worked in round 1; 269 crashed)
  float* ws = (float*)d_ws;
  float* f      = ws;               // 5,120,000
  float* sz     = f  + 5120000;     // 10,240,000
  float* u      = sz + 10240000;    // 10,240,000
  float* dl     = u  + 10240000;    // 10,240,000
  float* Bv     = dl + 10240000;    // 10,240,000
  float* Cv     = Bv + 10240000;    // 10,240,000
  float* Sc     = Cv + 10240000;    // 655,360
  float* Pc     = Sc + 655360;      // 655,360
  float* h0     = Pc + 655360;      // 655,360
  float* pooled = h0 + 655360;      // 8,192
  float* wt1    = pooled + 8192;    // 1,536
  short* wt2b   = (short*)(wt1 + 1536);  // 12,288 shorts
  short* wt3b   = wt2b + 12288;          // 12,288 shorts

  k_wt<<<102,256,0,stream>>>(c1w, c2w, c3w, wt1, wt2b, wt3b);
  k_embed<<<2500,256,0,stream>>>(x, idx, embed, f);
  for (int l=0;l<NL;l++){
    k_pre<<<2500,256,0,stream>>>(f, norm_w + l*8, in_proj + l*256, conv_w + l*48,
         conv_b + l*16, x_proj + l*528, dt_w + l*16, dt_b + l*16, sz, u, dl, Bv, Cv);
    k_scan_p1<<<dim3(NCH,B),256,0,stream>>>(dl, u, Bv, A_log + l*256, Sc, Pc);
    k_scan_p2<<<B,256,0,stream>>>(Sc, Pc, h0);
    k_scan_p3o<<<dim3(NCH,B),256,0,stream>>>(dl, u, Bv, Cv, h0, A_log + l*256, Dp + l*16,
         sz, out_w + l*128, f);
  }
  hipMemsetAsync(pooled, 0, B*64*sizeof(float), stream);
  k_head<<<dim3(79,B),256,0,stream>>>(f, wt1, c1b, wt2b, c2b, wt3b, c3b, pooled);
  k_fc<<<(B*NC+255)/256,256,0,stream>>>(pooled, fcw, fcb, out);
}

// Round 6
// 1862.434 us; speedup vs baseline: 6.1911x; 1.1631x over previous
//
#include <hip/hip_runtime.h>
#include <math.h>

#define B 128
#define L 5000
#define NL 4
#define NCH 20
#define LC 250
#define ST 50
#define HT 64

typedef __attribute__((ext_vector_type(8))) short bf16x8;
typedef __attribute__((ext_vector_type(4))) short short4v;
typedef __attribute__((ext_vector_type(4))) float f32x4;

__device__ __forceinline__ float sigmoidf_(float x){ return 1.f/(1.f+__expf(-x)); }
__device__ __forceinline__ float siluf_(float x){ return x*sigmoidf_(x); }
__device__ __forceinline__ float softplusf_(float x){ return fmaxf(x,0.f) + log1pf(__expf(-fabsf(x))); }
__device__ __forceinline__ short bfc_(float x){
  union { float f; unsigned u; } v; v.f = x;
  unsigned r = v.u + 0x7fffu + ((v.u >> 16) & 1u);
  return (short)(r >> 16);
}
__device__ __forceinline__ float b2f_(short s){
  union { unsigned u; float f; } v; v.u = ((unsigned)(unsigned short)s) << 16;
  return v.f;
}
// LDS swizzle for [row][64-short] tiles: XOR 8-short slot by row&7 (T2)
#define SW(row, col) (((row)<<6) + ((col) ^ (((row)&7)<<3)))

// ---------------- f0 = embed[idx] * x ----------------
__global__ void k_embed(const float* __restrict__ x, const int* __restrict__ idx,
                        const float* __restrict__ embed, float* __restrict__ f){
  int gid = blockIdx.x*256 + threadIdx.x; // b*L + t
  if (gid >= B*L) return;
  int t = gid % L;
  float xv = x[gid];
  const float* er = embed + (size_t)idx[t]*8;
  float4 e0 = *(const float4*)(er);
  float4 e1 = *(const float4*)(er+4);
  *(float4*)(f + (size_t)gid*8)   = make_float4(e0.x*xv, e0.y*xv, e0.z*xv, e0.w*xv);
  *(float4*)(f + (size_t)gid*8+4) = make_float4(e1.x*xv, e1.y*xv, e1.z*xv, e1.w*xv);
}

// ---------------- fused layer pass 1: preprocess + per-chunk scan -> Sc, Pc ----------------
__global__ __launch_bounds__(256) void k_l1(const float* __restrict__ f,
    const float* __restrict__ norm_w, const float* __restrict__ in_proj,
    const float* __restrict__ conv_w, const float* __restrict__ conv_b,
    const float* __restrict__ x_proj, const float* __restrict__ dt_w,
    const float* __restrict__ dt_b, const float* __restrict__ A_log,
    float* __restrict__ Sc, float* __restrict__ Pc){
  __shared__ float s_ipnw[128], s_cw[48], s_cb[16], s_xpB[272], s_dtw[16], s_dtb[16];
  __shared__ float fsub[52][8], rn[52], xc[52][16];
  __shared__ float uL[50][16], BL[50][16], dlL[50][16], dbc0[50];
  int tid = threadIdx.x, ch = blockIdx.x, b = blockIdx.y;
  if (tid < 128) s_ipnw[tid] = in_proj[tid]*norm_w[tid&7];
  if (tid >= 128 && tid < 176) s_cw[tid-128] = conv_w[tid-128];
  if (tid >= 192 && tid < 208) s_cb[tid-192] = conv_b[tid-192];
  if (tid >= 208 && tid < 224) s_dtw[tid-208] = dt_w[tid-208];
  if (tid >= 224 && tid < 240) s_dtb[tid-224] = dt_b[tid-224];
  for (int i=tid;i<272;i+=256) s_xpB[i] = x_proj[i];
  int e = tid>>4, n = tid&15;
  float a = -__expf(A_log[e*16+n]);
  float h = 0.f, dsum = 0.f;
  int t00 = ch*LC;
  for (int sub=0; sub<LC/ST; sub++){
    int ts = t00 + sub*ST;
    __syncthreads();
    for (int i=tid;i<416;i+=256){ int r=i>>3, d=i&7; int t=ts-2+r;
      fsub[r][d] = (t>=0) ? f[((size_t)b*L+t)*8+d] : 0.f; }
    __syncthreads();
    if (tid < 52){ float ss=0.f;
      #pragma unroll
      for (int d=0;d<8;d++){ float v=fsub[tid][d]; ss += v*v; }
      rn[tid] = rsqrtf(ss*0.125f + 1e-5f); }
    __syncthreads();
    for (int i=tid;i<832;i+=256){ int r=i>>4, c=i&15; int t=ts-2+r;
      float acc=0.f;
      #pragma unroll
      for (int d=0;d<8;d++) acc += s_ipnw[c*8+d]*fsub[r][d];
      xc[r][c] = (t>=0) ? acc*rn[r] : 0.f; }
    __syncthreads();
    for (int i=tid;i<800;i+=256){ int j=i>>4, c=i&15;
      float acc = s_cb[c] + s_cw[c*3]*xc[j][c] + s_cw[c*3+1]*xc[j+1][c] + s_cw[c*3+2]*xc[j+2][c];
      uL[j][c] = siluf_(acc); }
    __syncthreads();
    for (int i=tid;i<800;i+=256){ int j=i>>4, nn=i&15;
      float acc=0.f;
      #pragma unroll
      for (int c=0;c<16;c++) acc += s_xpB[(1+nn)*16+c]*uL[j][c];
      BL[j][nn] = acc;
      if (nn==0){ float s=0.f;
        #pragma unroll
        for (int c=0;c<16;c++) s += s_xpB[c]*uL[j][c];
        dbc0[j] = s; } }
    __syncthreads();
    for (int i=tid;i<800;i+=256){ int j=i>>4, ee=i&15;
      dlL[j][ee] = softplusf_(dbc0[j]*s_dtw[ee] + s_dtb[ee]); }
    __syncthreads();
    for (int j=0;j<ST;j++){
      float d = dlL[j][e], uu = uL[j][e], bb = BL[j][n];
      h = __expf(d*a)*h + d*bb*uu;
      dsum += d;
    }
  }
  size_t o = ((size_t)b*NCH + ch)*256 + tid;
  Sc[o] = h;
  Pc[o] = __expf(a*dsum);
}

// ---------------- pass 2: serial scan over chunks -> h0 ----------------
__global__ __launch_bounds__(256) void k_scan_p2(const float* __restrict__ Sc, const float* __restrict__ Pc,
    float* __restrict__ h0){
  int tid = threadIdx.x;
  int b = blockIdx.x;
  float h = 0.f;
  for (int ch=0; ch<NCH; ch++){
    size_t o = ((size_t)b*NCH + ch)*256 + tid;
    h0[o] = h;
    h = Pc[o]*h + Sc[o];
  }
}

// ---------------- fused layer pass 3: preprocess + scan + gated out_proj -> fout ----------------
__global__ __launch_bounds__(256) void k_l3(const float* __restrict__ fin, float* __restrict__ fout,
    const float* __restrict__ norm_w, const float* __restrict__ in_proj,
    const float* __restrict__ conv_w, const float* __restrict__ conv_b,
    const float* __restrict__ x_proj, const float* __restrict__ dt_w,
    const float* __restrict__ dt_b, const float* __restrict__ A_log,
    const float* __restrict__ Dp, const float* __restrict__ h0,
    const float* __restrict__ ow){
  __shared__ float s_ipnw[256], s_cw[48], s_cb[16], s_xp[528], s_dtw[16], s_dtb[16], s_ow[128];
  __shared__ float fsub[52][8], rn[52], xc[52][16];
  __shared__ float uL[50][16], BL[50][16], CL[50][16], dlL[50][16], szL[50][16], yL[50][16], dbc0[50];
  int tid = threadIdx.x, ch = blockIdx.x, b = blockIdx.y;
  s_ipnw[tid] = in_proj[tid]*norm_w[tid&7];
  for (int i=tid;i<528;i+=256) s_xp[i] = x_proj[i];
  if (tid < 48) s_cw[tid] = conv_w[tid];
  if (tid >= 64 && tid < 80) s_cb[tid-64] = conv_b[tid-64];
  if (tid >= 80 && tid < 96) s_dtw[tid-80] = dt_w[tid-80];
  if (tid >= 96 && tid < 112) s_dtb[tid-96] = dt_b[tid-96];
  if (tid >= 112 && tid < 240) s_ow[tid-112] = ow[tid-112];
  int e = tid>>4, n = tid&15;
  float a = -__expf(A_log[e*16+n]);
  float De = Dp[e];
  float h = h0[((size_t)b*NCH + ch)*256 + tid];
  int t00 = ch*LC;
  for (int sub=0; sub<LC/ST; sub++){
    int ts = t00 + sub*ST;
    __syncthreads();
    for (int i=tid;i<416;i+=256){ int r=i>>3, d=i&7; int t=ts-2+r;
      fsub[r][d] = (t>=0) ? fin[((size_t)b*L+t)*8+d] : 0.f; }
    __syncthreads();
    if (tid < 52){ float ss=0.f;
      #pragma unroll
      for (int d=0;d<8;d++){ float v=fsub[tid][d]; ss += v*v; }
      rn[tid] = rsqrtf(ss*0.125f + 1e-5f); }
    __syncthreads();
    for (int i=tid;i<832;i+=256){ int r=i>>4, c=i&15; int t=ts-2+r;
      float acc=0.f;
      #pragma unroll
      for (int d=0;d<8;d++) acc += s_ipnw[c*8+d]*fsub[r][d];
      xc[r][c] = (t>=0) ? acc*rn[r] : 0.f; }
    for (int i=tid;i<800;i+=256){ int j=i>>4, c=i&15; int r=j+2;
      float acc=0.f;
      #pragma unroll
      for (int d=0;d<8;d++) acc += s_ipnw[(16+c)*8+d]*fsub[r][d];
      szL[j][c] = siluf_(acc*rn[r]); }
    __syncthreads();
    for (int i=tid;i<800;i+=256){ int j=i>>4, c=i&15;
      float acc = s_cb[c] + s_cw[c*3]*xc[j][c] + s_cw[c*3+1]*xc[j+1][c] + s_cw[c*3+2]*xc[j+2][c];
      uL[j][c] = siluf_(acc); }
    __syncthreads();
    for (int i=tid;i<800;i+=256){ int j=i>>4, nn=i&15;
      float accB=0.f, accC=0.f;
      #pragma unroll
      for (int c=0;c<16;c++){
        float uv = uL[j][c];
        accB += s_xp[(1+nn)*16+c]*uv;
        accC += s_xp[(17+nn)*16+c]*uv;
      }
      BL[j][nn] = accB; CL[j][nn] = accC;
      if (nn==0){ float s=0.f;
        #pragma unroll
        for (int c=0;c<16;c++) s += s_xp[c]*uL[j][c];
        dbc0[j] = s; } }
    __syncthreads();
    for (int i=tid;i<800;i+=256){ int j=i>>4, ee=i&15;
      dlL[j][ee] = softplusf_(dbc0[j]*s_dtw[ee] + s_dtb[ee]); }
    __syncthreads();
    for (int j=0;j<ST;j++){
      float d = dlL[j][e], uu = uL[j][e], bb = BL[j][n], cc = CL[j][n];
      h = __expf(d*a)*h + d*bb*uu;
      float p = h*cc;
      p += __shfl_xor(p, 1, 64);
      p += __shfl_xor(p, 2, 64);
      p += __shfl_xor(p, 4, 64);
      p += __shfl_xor(p, 8, 64);
      if (n == 0) yL[j][e] = p + De*uu;
    }
    __syncthreads();
    for (int i=tid;i<400;i+=256){ int j=i>>3, d=i&7;
      size_t fi = ((size_t)b*L + ts + j)*8 + d;
      float acc = fsub[j+2][d];
      #pragma unroll
      for (int e2=0;e2<16;e2++) acc += s_ow[d*16+e2]*yL[j][e2]*szL[j][e2];
      fout[fi] = acc; }
  }
}

// ---------------- head weight prep ----------------
__global__ void k_wt(const float* __restrict__ c1w, const float* __restrict__ c2w,
                     const float* __restrict__ c3w, float* __restrict__ wt1,
                     short* __restrict__ wt2b, short* __restrict__ wt3b){
  int idx = blockIdx.x*256 + threadIdx.x;
  if (idx < 1536){
    int r = idx >> 6, c = idx & 63;
    wt1[idx] = c1w[c*24 + r];
  } else if (idx < 1536 + 12288){
    int i = idx - 1536;
    int c = i / 192, rem = i % 192;
    int k = rem >> 6, ci = rem & 63;
    wt2b[i] = bfc_(c2w[c*192 + ci*3 + k]);
  } else if (idx < 1536 + 24576){
    int i = idx - 1536 - 12288;
    int c = i / 192, rem = i % 192;
    int k = rem >> 6, ci = rem & 63;
    wt3b[i] = bfc_(c3w[c*192 + ci*3 + k]);
  }
}

// ---------------- fused head: c1 fp32 -> MFMA c2/c3 (bf16), swizzled LDS ----------------
__global__ __launch_bounds__(256) void k_head(const float* __restrict__ f,
   const float* __restrict__ wt1, const float* __restrict__ c1b,
   const short* __restrict__ wt2b, const float* __restrict__ c2b,
   const short* __restrict__ wt3b, const float* __restrict__ c3b,
   float* __restrict__ pooled){
  __shared__ float fs[8][72];
  __shared__ float s_c1b[64];
  __shared__ short h1t[84*64];   // [time 0..83][ci 0..63], XOR-swizzled
  __shared__ short h2t[66*64];
  int tid  = threadIdx.x;
  int b    = blockIdx.y;
  int t0   = blockIdx.x * HT;
  int lane = tid & 63;
  int w    = tid >> 6;
  int cb   = w*16;

  for (int task = tid; task < 560; task += 256){
    int d = task & 7, r = task >> 3;
    int t = t0 - 3 + r;
    fs[d][r] = (t >= 0 && t < L) ? f[((size_t)b*L + t)*8 + d] : 0.f;
  }
  if (tid < 64) s_c1b[tid] = c1b[tid];
  __syncthreads();

  // phase A: c1 fp32 -> h1t bf16 (time rows 0..67; t1 = t0-2+row)
  #pragma unroll
  for (int rep = 0; rep < 2; rep++){
    int col = lane + rep*64;
    if (col < 68){
      int t1 = t0 - 2 + col;
      bool valid = (t1 >= 0 && t1 < L);
      float acc[16];
      #pragma unroll
      for (int cc=0; cc<16; cc++) acc[cc] = s_c1b[cb+cc];
      #pragma unroll
      for (int k=0;k<3;k++){
        #pragma unroll
        for (int d=0; d<8; d++){
          float fv = fs[d][col + k];
          const float* wr = wt1 + (d*3+k)*64 + cb;
          #pragma unroll
          for (int cc=0; cc<16; cc++) acc[cc] += wr[cc]*fv;
        }
      }
      bf16x8 v0, v1;
      #pragma unroll
      for (int i=0;i<8;i++){
        v0[i] = bfc_(valid ? fmaxf(acc[i],0.f)   : 0.f);
        v1[i] = bfc_(valid ? fmaxf(acc[8+i],0.f) : 0.f);
      }
      *(bf16x8*)&h1t[SW(col, cb)]     = v0;
      *(bf16x8*)&h1t[SW(col, cb + 8)] = v1;
    }
  }
  __syncthreads();

  // c2: M=64(c) K=192 N=16-col tiles over time
  {
    const short* wA = wt2b + (cb + (lane&15))*192 + ((lane>>4)*8);
    bf16x8 a2[6];
    #pragma unroll
    for (int s=0;s<6;s++) a2[s] = *(const bf16x8*)(wA + 32*s);
    f32x4 bias2 = *(const f32x4*)(c2b + cb + ((lane>>4)<<2));
    #pragma unroll
    for (int nt=0; nt<5; nt++){
      f32x4 acc = {0.f,0.f,0.f,0.f};
      #pragma unroll
      for (int s=0;s<6;s++){
        int k = s>>1, ci0 = (s&1)*32;
        int jr = nt*16 + (lane&15) + k;
        bf16x8 bfr = *(bf16x8*)&h1t[SW(jr, ci0 + ((lane>>4)*8))];
        acc = __builtin_amdgcn_mfma_f32_16x16x32_bf16(a2[s], bfr, acc, 0, 0, 0);
      }
      int tr = nt*16 + (lane&15);
      if (tr < 66){
        int tg = t0 - 1 + tr;
        bool v = (tg >= 0 && tg < L);
        short4v pk;
        #pragma unroll
        for (int reg=0;reg<4;reg++)
          pk[reg] = bfc_(v ? fmaxf(acc[reg] + bias2[reg], 0.f) : 0.f);
        *(short4v*)&h2t[SW(tr, cb + ((lane>>4)<<2))] = pk;
      }
    }
  }
  __syncthreads();

  // c3 + residual relu + pool
  {
    const short* wA = wt3b + (cb + (lane&15))*192 + ((lane>>4)*8);
    bf16x8 a3[6];
    #pragma unroll
    for (int s=0;s<6;s++) a3[s] = *(const bf16x8*)(wA + 32*s);
    f32x4 bias3 = *(const f32x4*)(c3b + cb + ((lane>>4)<<2));
    int c0 = cb + ((lane>>4)<<2);
    float pool[4] = {0.f,0.f,0.f,0.f};
    #pragma unroll
    for (int nt=0; nt<4; nt++){
      f32x4 acc = {0.f,0.f,0.f,0.f};
      #pragma unroll
      for (int s=0;s<6;s++){
        int k = s>>1, ci0 = (s&1)*32;
        int jr = nt*16 + (lane&15) + k;
        bf16x8 bfr = *(bf16x8*)&h2t[SW(jr, ci0 + ((lane>>4)*8))];
        acc = __builtin_amdgcn_mfma_f32_16x16x32_bf16(a3[s], bfr, acc, 0, 0, 0);
      }
      int t = t0 + nt*16 + (lane&15);
      short4v hres = *(short4v*)&h1t[SW(nt*16 + (lane&15) + 2, c0)];
      if (t < L){
        #pragma unroll
        for (int reg=0;reg<4;reg++)
          pool[reg] += fmaxf(b2f_(hres[reg]) + acc[reg] + bias3[reg], 0.f);
      }
    }
    #pragma unroll
    for (int m=1; m<16; m<<=1){
      #pragma unroll
      for (int reg=0;reg<4;reg++) pool[reg] += __shfl_xor(pool[reg], m, 64);
    }
    if ((lane & 15) == 0){
      #pragma unroll
      for (int reg=0;reg<4;reg++) atomicAdd(&pooled[b*64 + c0 + reg], pool[reg]);
    }
  }
}

// ---------------- final FC ----------------
__global__ void k_fc(const float* __restrict__ pooled, const float* __restrict__ fcw,
                     const float* __restrict__ fcb, float* __restrict__ out){
  int gid = blockIdx.x*256 + threadIdx.x;
  if (gid >= B*230) return;
  int b = gid / 230, j = gid % 230;
  const float* p = pooled + b*64;
  const float* wv = fcw + j*64;
  float a = 0.f;
  #pragma unroll
  for (int c=0;c<64;c++) a += p[c]*wv[c];
  out[gid] = a*(1.f/(float)L) + fcb[j];
}

extern "C" void kernel_launch(void* const* d_in, const int* in_sizes, int n_in,
                              void* d_out, int out_size, void* d_ws, size_t ws_size,
                              hipStream_t stream){
  const float* x      = (const float*)d_in[0];
  const int*   idx    = (const int*)  d_in[1];
  const float* embed  = (const float*)d_in[2];
  const float* norm_w = (const float*)d_in[3];
  const float* in_proj= (const float*)d_in[4];
  const float* conv_w = (const float*)d_in[5];
  const float* conv_b = (const float*)d_in[6];
  const float* x_proj = (const float*)d_in[7];
  const float* dt_w   = (const float*)d_in[8];
  const float* dt_b   = (const float*)d_in[9];
  const float* A_log  = (const float*)d_in[10];
  const float* Dp     = (const float*)d_in[11];
  const float* out_w  = (const float*)d_in[12];
  const float* c1w    = (const float*)d_in[13];
  const float* c1b    = (const float*)d_in[14];
  const float* c2w    = (const float*)d_in[15];
  const float* c2b    = (const float*)d_in[16];
  const float* c3w    = (const float*)d_in[17];
  const float* c3b    = (const float*)d_in[18];
  const float* fcw    = (const float*)d_in[19];
  const float* fcb    = (const float*)d_in[20];
  float* out = (float*)d_out;

  // workspace: ~12.2M floats = 49 MB
  float* ws = (float*)d_ws;
  float* f0     = ws;               // 5,120,000
  float* f1     = f0 + 5120000;     // 5,120,000
  float* Sc     = f1 + 5120000;     // 655,360
  float* Pc     = Sc + 655360;      // 655,360
  float* h0     = Pc + 655360;      // 655,360
  float* pooled = h0 + 655360;      // 8,192
  float* wt1    = pooled + 8192;    // 1,536
  short* wt2b   = (short*)(wt1 + 1536);  // 12,288 shorts
  short* wt3b   = wt2b + 12288;          // 12,288 shorts

  k_wt<<<102,256,0,stream>>>(c1w, c2w, c3w, wt1, wt2b, wt3b);
  k_embed<<<2500,256,0,stream>>>(x, idx, embed, f0);
  for (int l=0;l<NL;l++){
    const float* fin = (l & 1) ? f1 : f0;
    float*       fo  = (l & 1) ? f0 : f1;
    k_l1<<<dim3(NCH,B),256,0,stream>>>(fin, norm_w + l*8, in_proj + l*256, conv_w + l*48,
         conv_b + l*16, x_proj + l*528, dt_w + l*16, dt_b + l*16, A_log + l*256, Sc, Pc);
    k_scan_p2<<<B,256,0,stream>>>(Sc, Pc, h0);
    k_l3<<<dim3(NCH,B),256,0,stream>>>(fin, fo, norm_w + l*8, in_proj + l*256, conv_w + l*48,
         conv_b + l*16, x_proj + l*528, dt_w + l*16, dt_b + l*16, A_log + l*256,
         Dp + l*16, h0, out_w + l*128);
  }
  hipMemsetAsync(pooled, 0, B*64*sizeof(float), stream);
  k_head<<<dim3(79,B),256,0,stream>>>(f0, wt1, c1b, wt2b, c2b, wt3b, c3b, pooled);
  k_fc<<<(B*230+255)/256,256,0,stream>>>(pooled, fcw, fcb, out);
}

// Round 8
// 1765.349 us; speedup vs baseline: 6.5316x; 1.0550x over previous
//
#include <hip/hip_runtime.h>
#include <math.h>

#define B 128
#define L 5000
#define NL 4
#define NCH 25
#define LC 200
#define ST 50
#define HT 64

typedef __attribute__((ext_vector_type(8))) short bf16x8;
typedef __attribute__((ext_vector_type(4))) short short4v;
typedef __attribute__((ext_vector_type(4))) float f32x4;

__device__ __forceinline__ float sigmoidf_(float x){ return 1.f/(1.f+__expf(-x)); }
__device__ __forceinline__ float siluf_(float x){ return x*sigmoidf_(x); }
__device__ __forceinline__ float softplusf_(float x){ return fmaxf(x,0.f) + log1pf(__expf(-fabsf(x))); }
__device__ __forceinline__ short bfc_(float x){
  union { float f; unsigned u; } v; v.f = x;
  unsigned r = v.u + 0x7fffu + ((v.u >> 16) & 1u);
  return (short)(r >> 16);
}
__device__ __forceinline__ float b2f_(short s){
  union { unsigned u; float f; } v; v.u = ((unsigned)(unsigned short)s) << 16;
  return v.f;
}
// LDS swizzle for [row][64-short] tiles: XOR 8-short slot by row&7 (T2)
#define SW(row, col) (((row)<<6) + ((col) ^ (((row)&7)<<3)))

// ---------------- f0 = embed[idx] * x ----------------
__global__ void k_embed(const float* __restrict__ x, const int* __restrict__ idx,
                        const float* __restrict__ embed, float* __restrict__ f){
  int gid = blockIdx.x*256 + threadIdx.x; // b*L + t
  if (gid >= B*L) return;
  int t = gid % L;
  float xv = x[gid];
  const float* er = embed + (size_t)idx[t]*8;
  float4 e0 = *(const float4*)(er);
  float4 e1 = *(const float4*)(er+4);
  *(float4*)(f + (size_t)gid*8)   = make_float4(e0.x*xv, e0.y*xv, e0.z*xv, e0.w*xv);
  *(float4*)(f + (size_t)gid*8+4) = make_float4(e1.x*xv, e1.y*xv, e1.z*xv, e1.w*xv);
}

// ---------------- fused layer pass 1: preprocess + per-chunk scan -> Sc, Pc ----------------
__global__ __launch_bounds__(256) void k_l1(const float* __restrict__ f,
    const float* __restrict__ norm_w, const float* __restrict__ in_proj,
    const float* __restrict__ conv_w, const float* __restrict__ conv_b,
    const float* __restrict__ x_proj, const float* __restrict__ dt_w,
    const float* __restrict__ dt_b, const float* __restrict__ A_log,
    float* __restrict__ Sc, float* __restrict__ Pc){
  __shared__ float s_ipnw[128], s_cw[48], s_cb[16], s_xpB[272], s_dtw[16], s_dtb[16];
  __shared__ float fsub[52][8], rn[52];
  __shared__ float uL[50][16], BL[50][16], dlL[50][16], dbc0[50];
  int tid = threadIdx.x, ch = blockIdx.x, b = blockIdx.y;
  if (tid < 128) s_ipnw[tid] = in_proj[tid]*norm_w[tid&7];
  else if (tid < 176) s_cw[tid-128] = conv_w[tid-128];
  else if (tid >= 192 && tid < 208) s_cb[tid-192] = conv_b[tid-192];
  else if (tid >= 208 && tid < 224) s_dtw[tid-208] = dt_w[tid-208];
  else if (tid >= 224 && tid < 240) s_dtb[tid-224] = dt_b[tid-224];
  for (int i=tid;i<272;i+=256) s_xpB[i] = x_proj[i];
  int e = tid>>4, n = tid&15;
  float a = -__expf(A_log[e*16+n]);
  float h = 0.f, dsum = 0.f;
  int t00 = ch*LC;
  for (int sub=0; sub<LC/ST; sub++){
    int ts = t00 + sub*ST;
    __syncthreads();
    for (int i=tid;i<104;i+=256){ int r=i>>1, half=i&1; int t=ts-2+r;
      *(float4*)&fsub[r][half*4] = (t>=0) ? *(const float4*)&f[((size_t)b*L+t)*8+half*4]
                                          : make_float4(0.f,0.f,0.f,0.f); }
    __syncthreads();
    if (tid < 52){ float ss=0.f;
      #pragma unroll
      for (int d=0;d<8;d++){ float v=fsub[tid][d]; ss += v*v; }
      rn[tid] = rsqrtf(ss*0.125f + 1e-5f); }
    __syncthreads();
    for (int i=tid;i<800;i+=256){ int j=i>>4, c=i&15;
      float acc = s_cb[c];
      #pragma unroll
      for (int kk=0;kk<3;kk++){
        int r = j + kk;
        float dot=0.f;
        #pragma unroll
        for (int d=0;d<8;d++) dot += s_ipnw[c*8+d]*fsub[r][d];
        acc += s_cw[c*3+kk]*(dot*rn[r]);
      }
      uL[j][c] = siluf_(acc); }
    __syncthreads();
    for (int i=tid;i<800;i+=256){ int j=i>>4, nn=i&15;
      float acc=0.f;
      #pragma unroll
      for (int c=0;c<16;c++) acc += s_xpB[(1+nn)*16+c]*uL[j][c];
      BL[j][nn] = acc;
      if (nn==0){ float s=0.f;
        #pragma unroll
        for (int c=0;c<16;c++) s += s_xpB[c]*uL[j][c];
        dbc0[j] = s; } }
    __syncthreads();
    for (int i=tid;i<800;i+=256){ int j=i>>4, ee=i&15;
      dlL[j][ee] = softplusf_(dbc0[j]*s_dtw[ee] + s_dtb[ee]); }
    __syncthreads();
    for (int j=0;j<ST;j++){
      float d = dlL[j][e], uu = uL[j][e], bb = BL[j][n];
      h = __expf(d*a)*h + d*bb*uu;
      dsum += d;
    }
  }
  size_t o = ((size_t)b*NCH + ch)*256 + tid;
  Sc[o] = h;
  Pc[o] = __expf(a*dsum);
}

// ---------------- fused layer pass 3: h0 prefix + preprocess + scan + gated out_proj ----------------
__global__ __launch_bounds__(256) void k_l3(const float* __restrict__ fin, float* __restrict__ fout,
    const float* __restrict__ norm_w, const float* __restrict__ in_proj,
    const float* __restrict__ conv_w, const float* __restrict__ conv_b,
    const float* __restrict__ x_proj, const float* __restrict__ dt_w,
    const float* __restrict__ dt_b, const float* __restrict__ A_log,
    const float* __restrict__ Dp, const float* __restrict__ Sc,
    const float* __restrict__ Pc, const float* __restrict__ ow){
  __shared__ float s_ipnw[256], s_cw[48], s_cb[16], s_xp[528], s_dtw[16], s_dtb[16], s_ow[128];
  __shared__ float fsub[52][8], rn[52];
  __shared__ float uL[50][16], BL[50][16], CL[50][16], dlL[50][16], szL[50][16], yL[50][16], dbc0[50];
  int tid = threadIdx.x, ch = blockIdx.x, b = blockIdx.y;
  s_ipnw[tid] = in_proj[tid]*norm_w[tid&7];
  for (int i=tid;i<528;i+=256) s_xp[i] = x_proj[i];
  if (tid < 48) s_cw[tid] = conv_w[tid];
  else if (tid >= 64 && tid < 80) s_cb[tid-64] = conv_b[tid-64];
  else if (tid >= 80 && tid < 96) s_dtw[tid-80] = dt_w[tid-80];
  else if (tid >= 96 && tid < 112) s_dtb[tid-96] = dt_b[tid-96];
  else if (tid >= 112 && tid < 240) s_ow[tid-112] = ow[tid-112];
  int e = tid>>4, n = tid&15;
  float a = -__expf(A_log[e*16+n]);
  float De = Dp[e];
  // h0 prefix over previous chunks (was k_scan_p2)
  float h = 0.f;
  for (int c2=0; c2<ch; c2++){
    size_t o = ((size_t)b*NCH + c2)*256 + tid;
    h = Pc[o]*h + Sc[o];
  }
  int t00 = ch*LC;
  for (int sub=0; sub<LC/ST; sub++){
    int ts = t00 + sub*ST;
    __syncthreads();
    for (int i=tid;i<104;i+=256){ int r=i>>1, half=i&1; int t=ts-2+r;
      *(float4*)&fsub[r][half*4] = (t>=0) ? *(const float4*)&fin[((size_t)b*L+t)*8+half*4]
                                          : make_float4(0.f,0.f,0.f,0.f); }
    __syncthreads();
    if (tid < 52){ float ss=0.f;
      #pragma unroll
      for (int d=0;d<8;d++){ float v=fsub[tid][d]; ss += v*v; }
      rn[tid] = rsqrtf(ss*0.125f + 1e-5f); }
    __syncthreads();
    for (int i=tid;i<800;i+=256){ int j=i>>4, c=i&15;
      float acc = s_cb[c];
      #pragma unroll
      for (int kk=0;kk<3;kk++){
        int r = j + kk;
        float dot=0.f;
        #pragma unroll
        for (int d=0;d<8;d++) dot += s_ipnw[c*8+d]*fsub[r][d];
        acc += s_cw[c*3+kk]*(dot*rn[r]);
      }
      uL[j][c] = siluf_(acc); }
    for (int i=tid;i<800;i+=256){ int j=i>>4, c=i&15; int r=j+2;
      float dot=0.f;
      #pragma unroll
      for (int d=0;d<8;d++) dot += s_ipnw[(16+c)*8+d]*fsub[r][d];
      szL[j][c] = siluf_(dot*rn[r]); }
    __syncthreads();
    for (int i=tid;i<800;i+=256){ int j=i>>4, nn=i&15;
      float accB=0.f, accC=0.f;
      #pragma unroll
      for (int c=0;c<16;c++){
        float uv = uL[j][c];
        accB += s_xp[(1+nn)*16+c]*uv;
        accC += s_xp[(17+nn)*16+c]*uv;
      }
      BL[j][nn] = accB; CL[j][nn] = accC;
      if (nn==0){ float s=0.f;
        #pragma unroll
        for (int c=0;c<16;c++) s += s_xp[c]*uL[j][c];
        dbc0[j] = s; } }
    __syncthreads();
    for (int i=tid;i<800;i+=256){ int j=i>>4, ee=i&15;
      dlL[j][ee] = softplusf_(dbc0[j]*s_dtw[ee] + s_dtb[ee]); }
    __syncthreads();
    for (int j=0;j<ST;j++){
      float d = dlL[j][e], uu = uL[j][e], bb = BL[j][n], cc = CL[j][n];
      h = __expf(d*a)*h + d*bb*uu;
      float p = h*cc;
      p += __shfl_xor(p, 1, 64);
      p += __shfl_xor(p, 2, 64);
      p += __shfl_xor(p, 4, 64);
      p += __shfl_xor(p, 8, 64);
      if (n == 0) yL[j][e] = p + De*uu;
    }
    __syncthreads();
    for (int i=tid;i<400;i+=256){ int j=i>>3, d=i&7;
      size_t fi = ((size_t)b*L + ts + j)*8 + d;
      float acc = fsub[j+2][d];
      #pragma unroll
      for (int e2=0;e2<16;e2++) acc += s_ow[d*16+e2]*yL[j][e2]*szL[j][e2];
      fout[fi] = acc; }
  }
}

// ---------------- head weight prep: wt1b [c][32] (m=kk*8+d, pad0); wt2b/wt3b [c][k*64+ci] ----------------
__global__ void k_wt(const float* __restrict__ c1w, const float* __restrict__ c2w,
                     const float* __restrict__ c3w, short* __restrict__ wt1b,
                     short* __restrict__ wt2b, short* __restrict__ wt3b){
  int idx = blockIdx.x*256 + threadIdx.x;
  if (idx < 2048){
    int c = idx >> 5, m = idx & 31;
    int kk = m >> 3, d = m & 7;
    wt1b[idx] = (kk < 3) ? bfc_(c1w[c*24 + d*3 + kk]) : (short)0;
  } else if (idx < 2048 + 12288){
    int i = idx - 2048;
    int c = i / 192, rem = i % 192;
    int k = rem >> 6, ci = rem & 63;
    wt2b[i] = bfc_(c2w[c*192 + ci*3 + k]);
  } else if (idx < 2048 + 24576){
    int i = idx - 2048 - 12288;
    int c = i / 192, rem = i % 192;
    int k = rem >> 6, ci = rem & 63;
    wt3b[i] = bfc_(c3w[c*192 + ci*3 + k]);
  }
}

// ---------------- fused head: all three convs via bf16 MFMA ----------------
__global__ __launch_bounds__(256) void k_head(const float* __restrict__ f,
   const short* __restrict__ wt1b, const float* __restrict__ c1b,
   const short* __restrict__ wt2b, const float* __restrict__ c2b,
   const short* __restrict__ wt3b, const float* __restrict__ c3b,
   float* __restrict__ pooled){
  __shared__ short fs_b[84*8];   // [r][d] bf16, r = t-(t0-3), rows 70..83 zero
  __shared__ short h1t[84*64];   // [time][ci], XOR-swizzled
  __shared__ short h2t[66*64];
  int tid  = threadIdx.x;
  int b    = blockIdx.y;
  int t0   = blockIdx.x * HT;
  int lane = tid & 63;
  int w    = tid >> 6;
  int cb   = w*16;
  int lc   = lane & 15, g = lane >> 4;

  for (int task = tid; task < 672; task += 256){
    int r = task >> 3, d = task & 7;
    int t = t0 - 3 + r;
    float v = (r < 70 && t >= 0 && t < L) ? f[((size_t)b*L + t)*8 + d] : 0.f;
    fs_b[task] = bfc_(v);
  }
  __syncthreads();

  // phase A: c1 via MFMA (M=64 ch, K=32 (24 real), N=80 time cols; valid cols 0..67)
  {
    bf16x8 a1 = *(const bf16x8*)(wt1b + (cb + lc)*32 + g*8);
    f32x4 bias1 = *(const f32x4*)(c1b + cb + (g<<2));
    #pragma unroll
    for (int nt=0; nt<5; nt++){
      int tcol = nt*16 + lc;
      bf16x8 bv = {0,0,0,0,0,0,0,0};
      if (g < 3) bv = *(bf16x8*)&fs_b[(tcol+g)*8];
      f32x4 acc = {0.f,0.f,0.f,0.f};
      acc = __builtin_amdgcn_mfma_f32_16x16x32_bf16(a1, bv, acc, 0, 0, 0);
      if (tcol < 68){
        int t1 = t0 - 2 + tcol;
        bool v = (t1 >= 0 && t1 < L);
        short4v pk;
        #pragma unroll
        for (int reg=0;reg<4;reg++)
          pk[reg] = bfc_(v ? fmaxf(acc[reg] + bias1[reg], 0.f) : 0.f);
        *(short4v*)&h1t[SW(tcol, cb + (g<<2))] = pk;
      }
    }
  }
  __syncthreads();

  // c2: M=64(c) K=192 N=16-col tiles over time
  {
    const short* wA = wt2b + (cb + lc)*192 + g*8;
    bf16x8 a2[6];
    #pragma unroll
    for (int s=0;s<6;s++) a2[s] = *(const bf16x8*)(wA + 32*s);
    f32x4 bias2 = *(const f32x4*)(c2b + cb + (g<<2));
    #pragma unroll
    for (int nt=0; nt<5; nt++){
      f32x4 acc = {0.f,0.f,0.f,0.f};
      #pragma unroll
      for (int s=0;s<6;s++){
        int k = s>>1, ci0 = (s&1)*32;
        int jr = nt*16 + lc + k;
        bf16x8 bfr = *(bf16x8*)&h1t[SW(jr, ci0 + g*8)];
        acc = __builtin_amdgcn_mfma_f32_16x16x32_bf16(a2[s], bfr, acc, 0, 0, 0);
      }
      int tr = nt*16 + lc;
      if (tr < 66){
        int tg = t0 - 1 + tr;
        bool v = (tg >= 0 && tg < L);
        short4v pk;
        #pragma unroll
        for (int reg=0;reg<4;reg++)
          pk[reg] = bfc_(v ? fmaxf(acc[reg] + bias2[reg], 0.f) : 0.f);
        *(short4v*)&h2t[SW(tr, cb + (g<<2))] = pk;
      }
    }
  }
  __syncthreads();

  // c3 + residual relu + pool
  {
    const short* wA = wt3b + (cb + lc)*192 + g*8;
    bf16x8 a3[6];
    #pragma unroll
    for (int s=0;s<6;s++) a3[s] = *(const bf16x8*)(wA + 32*s);
    f32x4 bias3 = *(const f32x4*)(c3b + cb + (g<<2));
    int c0 = cb + (g<<2);
    float pool[4] = {0.f,0.f,0.f,0.f};
    #pragma unroll
    for (int nt=0; nt<4; nt++){
      f32x4 acc = {0.f,0.f,0.f,0.f};
      #pragma unroll
      for (int s=0;s<6;s++){
        int k = s>>1, ci0 = (s&1)*32;
        int jr = nt*16 + lc + k;
        bf16x8 bfr = *(bf16x8*)&h2t[SW(jr, ci0 + g*8)];
        acc = __builtin_amdgcn_mfma_f32_16x16x32_bf16(a3[s], bfr, acc, 0, 0, 0);
      }
      int t = t0 + nt*16 + lc;
      short4v hres = *(short4v*)&h1t[SW(nt*16 + lc + 2, c0)];
      if (t < L){
        #pragma unroll
        for (int reg=0;reg<4;reg++)
          pool[reg] += fmaxf(b2f_(hres[reg]) + acc[reg] + bias3[reg], 0.f);
      }
    }
    #pragma unroll
    for (int m=1; m<16; m<<=1){
      #pragma unroll
      for (int reg=0;reg<4;reg++) pool[reg] += __shfl_xor(pool[reg], m, 64);
    }
    if (lc == 0){
      #pragma unroll
      for (int reg=0;reg<4;reg++) atomicAdd(&pooled[b*64 + c0 + reg], pool[reg]);
    }
  }
}

// ---------------- final FC ----------------
__global__ void k_fc(const float* __restrict__ pooled, const float* __restrict__ fcw,
                     const float* __restrict__ fcb, float* __restrict__ out){
  int gid = blockIdx.x*256 + threadIdx.x;
  if (gid >= B*230) return;
  int b = gid / 230, j = gid % 230;
  const float* p = pooled + b*64;
  const float* wv = fcw + j*64;
  float a = 0.f;
  #pragma unroll
  for (int c=0;c<64;c++) a += p[c]*wv[c];
  out[gid] = a*(1.f/(float)L) + fcb[j];
}

extern "C" void kernel_launch(void* const* d_in, const int* in_sizes, int n_in,
                              void* d_out, int out_size, void* d_ws, size_t ws_size,
                              hipStream_t stream){
  const float* x      = (const float*)d_in[0];
  const int*   idx    = (const int*)  d_in[1];
  const float* embed  = (const float*)d_in[2];
  const float* norm_w = (const float*)d_in[3];
  const float* in_proj= (const float*)d_in[4];
  const float* conv_w = (const float*)d_in[5];
  const float* conv_b = (const float*)d_in[6];
  const float* x_proj = (const float*)d_in[7];
  const float* dt_w   = (const float*)d_in[8];
  const float* dt_b   = (const float*)d_in[9];
  const float* A_log  = (const float*)d_in[10];
  const float* Dp     = (const float*)d_in[11];
  const float* out_w  = (const float*)d_in[12];
  const float* c1w    = (const float*)d_in[13];
  const float* c1b    = (const float*)d_in[14];
  const float* c2w    = (const float*)d_in[15];
  const float* c2b    = (const float*)d_in[16];
  const float* c3w    = (const float*)d_in[17];
  const float* c3b    = (const float*)d_in[18];
  const float* fcw    = (const float*)d_in[19];
  const float* fcb    = (const float*)d_in[20];
  float* out = (float*)d_out;

  // workspace: ~11.9M floats = 48 MB
  float* ws = (float*)d_ws;
  float* f0     = ws;               // 5,120,000
  float* f1     = f0 + 5120000;     // 5,120,000
  float* Sc     = f1 + 5120000;     // 819,200 (B*NCH*256)
  float* Pc     = Sc + 819200;      // 819,200
  float* pooled = Pc + 819200;      // 8,192
  short* wt1b   = (short*)(pooled + 8192);  // 2,048 shorts
  short* wt2b   = wt1b + 2048;              // 12,288 shorts
  short* wt3b   = wt2b + 12288;             // 12,288 shorts

  k_wt<<<104,256,0,stream>>>(c1w, c2w, c3w, wt1b, wt2b, wt3b);
  k_embed<<<2500,256,0,stream>>>(x, idx, embed, f0);
  for (int l=0;l<NL;l++){
    const float* fin = (l & 1) ? f1 : f0;
    float*       fo  = (l & 1) ? f0 : f1;
    k_l1<<<dim3(NCH,B),256,0,stream>>>(fin, norm_w + l*8, in_proj + l*256, conv_w + l*48,
         conv_b + l*16, x_proj + l*528, dt_w + l*16, dt_b + l*16, A_log + l*256, Sc, Pc);
    k_l3<<<dim3(NCH,B),256,0,stream>>>(fin, fo, norm_w + l*8, in_proj + l*256, conv_w + l*48,
         conv_b + l*16, x_proj + l*528, dt_w + l*16, dt_b + l*16, A_log + l*256,
         Dp + l*16, Sc, Pc, out_w + l*128);
  }
  (void)hipMemsetAsync(pooled, 0, B*64*sizeof(float), stream);
  k_head<<<dim3(79,B),256,0,stream>>>(f0, wt1b, c1b, wt2b, c2b, wt3b, c3b, pooled);
  k_fc<<<(B*230+255)/256,256,0,stream>>>(pooled, fcw, fcb, out);
}

// Round 9
// 1704.889 us; speedup vs baseline: 6.7632x; 1.0355x over previous
//
#include <hip/hip_runtime.h>
#include <math.h>

#define B 128
#define L 5000
#define NL 4
#define NCH 50
#define LC 100
#define ST 50
#define HT 64

typedef __attribute__((ext_vector_type(8))) short bf16x8;
typedef __attribute__((ext_vector_type(4))) short short4v;
typedef __attribute__((ext_vector_type(4))) float f32x4;

__device__ __forceinline__ float sigmoidf_(float x){ return 1.f/(1.f+__expf(-x)); }
__device__ __forceinline__ float siluf_(float x){ return x*sigmoidf_(x); }
__device__ __forceinline__ float softplusf_(float x){ return fmaxf(x,0.f) + log1pf(__expf(-fabsf(x))); }
__device__ __forceinline__ short bfc_(float x){
  union { float f; unsigned u; } v; v.f = x;
  unsigned r = v.u + 0x7fffu + ((v.u >> 16) & 1u);
  return (short)(r >> 16);
}
__device__ __forceinline__ float b2f_(short s){
  union { unsigned u; float f; } v; v.u = ((unsigned)(unsigned short)s) << 16;
  return v.f;
}
#define SW(row, col) (((row)<<6) + ((col) ^ (((row)&7)<<3)))

// ---------------- f0 = embed[idx] * x ----------------
__global__ void k_embed(const float* __restrict__ x, const int* __restrict__ idx,
                        const float* __restrict__ embed, float* __restrict__ f){
  int gid = blockIdx.x*256 + threadIdx.x;
  if (gid >= B*L) return;
  int t = gid % L;
  float xv = x[gid];
  const float* er = embed + (size_t)idx[t]*8;
  float4 e0 = *(const float4*)(er);
  float4 e1 = *(const float4*)(er+4);
  *(float4*)(f + (size_t)gid*8)   = make_float4(e0.x*xv, e0.y*xv, e0.z*xv, e0.w*xv);
  *(float4*)(f + (size_t)gid*8+4) = make_float4(e1.x*xv, e1.y*xv, e1.z*xv, e1.w*xv);
}

// ---------------- fused layer pass 1: preprocess + per-chunk scan -> Sc, Pc ----------------
__global__ __launch_bounds__(256,4) void k_l1(const float* __restrict__ fin,
    const float* __restrict__ norm_w, const float* __restrict__ in_proj,
    const float* __restrict__ conv_w, const float* __restrict__ conv_b,
    const float* __restrict__ x_proj, const float* __restrict__ dt_w,
    const float* __restrict__ dt_b, const float* __restrict__ A_log,
    float* __restrict__ Sc, float* __restrict__ Pc){
  __shared__ float fsub[52][8], rn[52];
  __shared__ float uL[ST][17];
  __shared__ float2 duL[ST][16];
  __shared__ float BLs[ST][17];
  __shared__ float dbc0[ST];
  int tid = threadIdx.x, ch = blockIdx.x, b = blockIdx.y;
  int e = tid>>4, n = tid&15;
  int ct = tid&15;                       // per-thread fixed 0..15 index
  // register-hoisted per-thread weight rows (all L2-resident)
  float ipnw_c[8], cwc[3];
  #pragma unroll
  for (int d=0;d<8;d++) ipnw_c[d] = in_proj[ct*8+d]*norm_w[d];
  #pragma unroll
  for (int k=0;k<3;k++) cwc[k] = conv_w[ct*3+k];
  float cbc = conv_b[ct];
  float xp0_c = x_proj[ct];
  float xpB_r[16];
  #pragma unroll
  for (int k=0;k<16;k++) xpB_r[k] = x_proj[(1+ct)*16+k];
  float dtw_e = dt_w[ct], dtb_e = dt_b[ct];
  float a = -__expf(A_log[e*16+n]);
  float h = 0.f, dsum = 0.f;
  int t00 = ch*LC;
  for (int sub=0; sub<LC/ST; sub++){
    int ts = t00 + sub*ST;
    __syncthreads();
    for (int i=tid;i<104;i+=256){ int r=i>>1, half=i&1; int t=ts-2+r;
      *(float4*)&fsub[r][half*4] = (t>=0) ? *(const float4*)&fin[((size_t)b*L+t)*8+half*4]
                                          : make_float4(0.f,0.f,0.f,0.f); }
    __syncthreads();
    if (tid < 52){ float ss=0.f;
      #pragma unroll
      for (int d=0;d<8;d++){ float v=fsub[tid][d]; ss += v*v; }
      rn[tid] = rsqrtf(ss*0.125f + 1e-5f); }
    __syncthreads();
    // u phase + dbc0 via 16-lane shfl reduce
    for (int i=tid;i<ST*16;i+=256){ int j=i>>4;
      float acc = cbc;
      #pragma unroll
      for (int kk=0;kk<3;kk++){
        int r = j + kk;
        float dot=0.f;
        #pragma unroll
        for (int d=0;d<8;d++) dot += ipnw_c[d]*fsub[r][d];
        acc += cwc[kk]*(dot*rn[r]);
      }
      float uv = siluf_(acc);
      uL[j][ct] = uv;
      float pp = xp0_c*uv;
      pp += __shfl_xor(pp, 1, 64);
      pp += __shfl_xor(pp, 2, 64);
      pp += __shfl_xor(pp, 4, 64);
      pp += __shfl_xor(pp, 8, 64);
      if (ct == 0) dbc0[j] = pp;
    }
    __syncthreads();
    // B + dl phase
    for (int i=tid;i<ST*16;i+=256){ int j=i>>4;
      float accB=0.f;
      #pragma unroll
      for (int c=0;c<16;c++) accB += xpB_r[c]*uL[j][c];
      BLs[j][ct] = accB;
      float dd = softplusf_(dbc0[j]*dtw_e + dtb_e);
      duL[j][ct] = make_float2(dd, dd*uL[j][ct]);
    }
    __syncthreads();
    for (int j=0;j<ST;j++){
      float2 du = duL[j][e];
      float bb = BLs[j][n];
      h = __expf(du.x*a)*h + du.y*bb;
      dsum += du.x;
    }
  }
  size_t o = ((size_t)b*NCH + ch)*256 + tid;
  Sc[o] = h;
  Pc[o] = __expf(a*dsum);
}

// ---------------- fused layer pass 3: h0 prefix + preprocess + scan + gated out_proj ----------------
__global__ __launch_bounds__(256,4) void k_l3(const float* __restrict__ fin, float* __restrict__ fout,
    const float* __restrict__ norm_w, const float* __restrict__ in_proj,
    const float* __restrict__ conv_w, const float* __restrict__ conv_b,
    const float* __restrict__ x_proj, const float* __restrict__ dt_w,
    const float* __restrict__ dt_b, const float* __restrict__ A_log,
    const float* __restrict__ Dp, const float* __restrict__ Sc,
    const float* __restrict__ Pc, const float* __restrict__ ow){
  __shared__ float fsub[52][8], rn[52];
  __shared__ float uL[ST][17], szL[ST][17], yL[ST][17];
  __shared__ float2 duL[ST][16], BCL[ST][16];
  __shared__ float dbc0[ST];
  __shared__ float s_owp[8*17], s_De[16];
  int tid = threadIdx.x, ch = blockIdx.x, b = blockIdx.y;
  int e = tid>>4, n = tid&15;
  int ct = tid&15;
  int dt8 = tid&7;
  float ipnw_c[8], ipnwz_c[8], cwc[3];
  #pragma unroll
  for (int d=0;d<8;d++){
    ipnw_c[d]  = in_proj[ct*8+d]*norm_w[d];
    ipnwz_c[d] = in_proj[(16+ct)*8+d]*norm_w[d];
  }
  #pragma unroll
  for (int k=0;k<3;k++) cwc[k] = conv_w[ct*3+k];
  float cbc = conv_b[ct];
  float xp0_c = x_proj[ct];
  float xpB_r[16], xpC_r[16];
  #pragma unroll
  for (int k=0;k<16;k++){
    xpB_r[k] = x_proj[(1+ct)*16+k];
    xpC_r[k] = x_proj[(17+ct)*16+k];
  }
  float dtw_e = dt_w[ct], dtb_e = dt_b[ct];
  float a = -__expf(A_log[e*16+n]);
  if (tid < 128) s_owp[(tid>>4)*17 + (tid&15)] = ow[tid];
  if (tid < 16) s_De[tid] = Dp[tid];
  // h0 prefix over previous chunks
  float h = 0.f;
  for (int c2=0; c2<ch; c2++){
    size_t o = ((size_t)b*NCH + c2)*256 + tid;
    h = Pc[o]*h + Sc[o];
  }
  int t00 = ch*LC;
  for (int sub=0; sub<LC/ST; sub++){
    int ts = t00 + sub*ST;
    __syncthreads();
    for (int i=tid;i<104;i+=256){ int r=i>>1, half=i&1; int t=ts-2+r;
      *(float4*)&fsub[r][half*4] = (t>=0) ? *(const float4*)&fin[((size_t)b*L+t)*8+half*4]
                                          : make_float4(0.f,0.f,0.f,0.f); }
    __syncthreads();
    if (tid < 52){ float ss=0.f;
      #pragma unroll
      for (int d=0;d<8;d++){ float v=fsub[tid][d]; ss += v*v; }
      rn[tid] = rsqrtf(ss*0.125f + 1e-5f); }
    __syncthreads();
    // u + sz phase + dbc0
    for (int i=tid;i<ST*16;i+=256){ int j=i>>4;
      float acc = cbc;
      #pragma unroll
      for (int kk=0;kk<3;kk++){
        int r = j + kk;
        float dot=0.f;
        #pragma unroll
        for (int d=0;d<8;d++) dot += ipnw_c[d]*fsub[r][d];
        acc += cwc[kk]*(dot*rn[r]);
      }
      float uv = siluf_(acc);
      uL[j][ct] = uv;
      int r2 = j + 2;
      float dz=0.f;
      #pragma unroll
      for (int d=0;d<8;d++) dz += ipnwz_c[d]*fsub[r2][d];
      szL[j][ct] = siluf_(dz*rn[r2]);
      float pp = xp0_c*uv;
      pp += __shfl_xor(pp, 1, 64);
      pp += __shfl_xor(pp, 2, 64);
      pp += __shfl_xor(pp, 4, 64);
      pp += __shfl_xor(pp, 8, 64);
      if (ct == 0) dbc0[j] = pp;
    }
    __syncthreads();
    // BC + dl phase
    for (int i=tid;i<ST*16;i+=256){ int j=i>>4;
      float accB=0.f, accC=0.f;
      #pragma unroll
      for (int c=0;c<16;c++){
        float uv = uL[j][c];
        accB += xpB_r[c]*uv;
        accC += xpC_r[c]*uv;
      }
      BCL[j][ct] = make_float2(accB, accC);
      float dd = softplusf_(dbc0[j]*dtw_e + dtb_e);
      duL[j][ct] = make_float2(dd, dd*uL[j][ct]);
    }
    __syncthreads();
    // scan
    for (int j=0;j<ST;j++){
      float2 du = duL[j][e];
      float2 bc = BCL[j][n];
      h = __expf(du.x*a)*h + du.y*bc.x;
      float p = h*bc.y;
      p += __shfl_xor(p, 1, 64);
      p += __shfl_xor(p, 2, 64);
      p += __shfl_xor(p, 4, 64);
      p += __shfl_xor(p, 8, 64);
      if (n == 0) yL[j][e] = p;
    }
    __syncthreads();
    // out_proj + residual (D*u folded in here)
    for (int i=tid;i<ST*8;i+=256){ int j=i>>3;
      size_t fi = ((size_t)b*L + ts + j)*8 + dt8;
      float acc = fsub[j+2][dt8];
      #pragma unroll
      for (int e2=0;e2<16;e2++){
        float ye = yL[j][e2] + s_De[e2]*uL[j][e2];
        acc += s_owp[dt8*17+e2]*ye*szL[j][e2];
      }
      fout[fi] = acc;
    }
  }
}

// ---------------- head weight prep ----------------
__global__ void k_wt(const float* __restrict__ c1w, const float* __restrict__ c2w,
                     const float* __restrict__ c3w, short* __restrict__ wt1b,
                     short* __restrict__ wt2b, short* __restrict__ wt3b){
  int idx = blockIdx.x*256 + threadIdx.x;
  if (idx < 2048){
    int c = idx >> 5, m = idx & 31;
    int kk = m >> 3, d = m & 7;
    wt1b[idx] = (kk < 3) ? bfc_(c1w[c*24 + d*3 + kk]) : (short)0;
  } else if (idx < 2048 + 12288){
    int i = idx - 2048;
    int c = i / 192, rem = i % 192;
    int k = rem >> 6, ci = rem & 63;
    wt2b[i] = bfc_(c2w[c*192 + ci*3 + k]);
  } else if (idx < 2048 + 24576){
    int i = idx - 2048 - 12288;
    int c = i / 192, rem = i % 192;
    int k = rem >> 6, ci = rem & 63;
    wt3b[i] = bfc_(c3w[c*192 + ci*3 + k]);
  }
}

// ---------------- fused head: all three convs via bf16 MFMA ----------------
__global__ __launch_bounds__(256) void k_head(const float* __restrict__ f,
   const short* __restrict__ wt1b, const float* __restrict__ c1b,
   const short* __restrict__ wt2b, const float* __restrict__ c2b,
   const short* __restrict__ wt3b, const float* __restrict__ c3b,
   float* __restrict__ pooled){
  __shared__ short fs_b[84*8];
  __shared__ short h1t[84*64];
  __shared__ short h2t[66*64];
  int tid  = threadIdx.x;
  int b    = blockIdx.y;
  int t0   = blockIdx.x * HT;
  int lane = tid & 63;
  int w    = tid >> 6;
  int cb   = w*16;
  int lc   = lane & 15, g = lane >> 4;

  for (int task = tid; task < 672; task += 256){
    int r = task >> 3, d = task & 7;
    int t = t0 - 3 + r;
    float v = (r < 70 && t >= 0 && t < L) ? f[((size_t)b*L + t)*8 + d] : 0.f;
    fs_b[task] = bfc_(v);
  }
  __syncthreads();

  {
    bf16x8 a1 = *(const bf16x8*)(wt1b + (cb + lc)*32 + g*8);
    f32x4 bias1 = *(const f32x4*)(c1b + cb + (g<<2));
    #pragma unroll
    for (int nt=0; nt<5; nt++){
      int tcol = nt*16 + lc;
      bf16x8 bv = {0,0,0,0,0,0,0,0};
      if (g < 3) bv = *(bf16x8*)&fs_b[(tcol+g)*8];
      f32x4 acc = {0.f,0.f,0.f,0.f};
      acc = __builtin_amdgcn_mfma_f32_16x16x32_bf16(a1, bv, acc, 0, 0, 0);
      if (tcol < 68){
        int t1 = t0 - 2 + tcol;
        bool v = (t1 >= 0 && t1 < L);
        short4v pk;
        #pragma unroll
        for (int reg=0;reg<4;reg++)
          pk[reg] = bfc_(v ? fmaxf(acc[reg] + bias1[reg], 0.f) : 0.f);
        *(short4v*)&h1t[SW(tcol, cb + (g<<2))] = pk;
      }
    }
  }
  __syncthreads();

  {
    const short* wA = wt2b + (cb + lc)*192 + g*8;
    bf16x8 a2[6];
    #pragma unroll
    for (int s=0;s<6;s++) a2[s] = *(const bf16x8*)(wA + 32*s);
    f32x4 bias2 = *(const f32x4*)(c2b + cb + (g<<2));
    #pragma unroll
    for (int nt=0; nt<5; nt++){
      f32x4 acc = {0.f,0.f,0.f,0.f};
      #pragma unroll
      for (int s=0;s<6;s++){
        int k = s>>1, ci0 = (s&1)*32;
        int jr = nt*16 + lc + k;
        bf16x8 bfr = *(bf16x8*)&h1t[SW(jr, ci0 + g*8)];
        acc = __builtin_amdgcn_mfma_f32_16x16x32_bf16(a2[s], bfr, acc, 0, 0, 0);
      }
      int tr = nt*16 + lc;
      if (tr < 66){
        int tg = t0 - 1 + tr;
        bool v = (tg >= 0 && tg < L);
        short4v pk;
        #pragma unroll
        for (int reg=0;reg<4;reg++)
          pk[reg] = bfc_(v ? fmaxf(acc[reg] + bias2[reg], 0.f) : 0.f);
        *(short4v*)&h2t[SW(tr, cb + (g<<2))] = pk;
      }
    }
  }
  __syncthreads();

  {
    const short* wA = wt3b + (cb + lc)*192 + g*8;
    bf16x8 a3[6];
    #pragma unroll
    for (int s=0;s<6;s++) a3[s] = *(const bf16x8*)(wA + 32*s);
    f32x4 bias3 = *(const f32x4*)(c3b + cb + (g<<2));
    int c0 = cb + (g<<2);
    float pool[4] = {0.f,0.f,0.f,0.f};
    #pragma unroll
    for (int nt=0; nt<4; nt++){
      f32x4 acc = {0.f,0.f,0.f,0.f};
      #pragma unroll
      for (int s=0;s<6;s++){
        int k = s>>1, ci0 = (s&1)*32;
        int jr = nt*16 + lc + k;
        bf16x8 bfr = *(bf16x8*)&h2t[SW(jr, ci0 + g*8)];
        acc = __builtin_amdgcn_mfma_f32_16x16x32_bf16(a3[s], bfr, acc, 0, 0, 0);
      }
      int t = t0 + nt*16 + lc;
      short4v hres = *(short4v*)&h1t[SW(nt*16 + lc + 2, c0)];
      if (t < L){
        #pragma unroll
        for (int reg=0;reg<4;reg++)
          pool[reg] += fmaxf(b2f_(hres[reg]) + acc[reg] + bias3[reg], 0.f);
      }
    }
    #pragma unroll
    for (int m=1; m<16; m<<=1){
      #pragma unroll
      for (int reg=0;reg<4;reg++) pool[reg] += __shfl_xor(pool[reg], m, 64);
    }
    if (lc == 0){
      #pragma unroll
      for (int reg=0;reg<4;reg++) atomicAdd(&pooled[b*64 + c0 + reg], pool[reg]);
    }
  }
}

// ---------------- final FC ----------------
__global__ void k_fc(const float* __restrict__ pooled, const float* __restrict__ fcw,
                     const float* __restrict__ fcb, float* __restrict__ out){
  int gid = blockIdx.x*256 + threadIdx.x;
  if (gid >= B*230) return;
  int b = gid / 230, j = gid % 230;
  const float* p = pooled + b*64;
  const float* wv = fcw + j*64;
  float a = 0.f;
  #pragma unroll
  for (int c=0;c<64;c++) a += p[c]*wv[c];
  out[gid] = a*(1.f/(float)L) + fcb[j];
}

extern "C" void kernel_launch(void* const* d_in, const int* in_sizes, int n_in,
                              void* d_out, int out_size, void* d_ws, size_t ws_size,
                              hipStream_t stream){
  const float* x      = (const float*)d_in[0];
  const int*   idx    = (const int*)  d_in[1];
  const float* embed  = (const float*)d_in[2];
  const float* norm_w = (const float*)d_in[3];
  const float* in_proj= (const float*)d_in[4];
  const float* conv_w = (const float*)d_in[5];
  const float* conv_b = (const float*)d_in[6];
  const float* x_proj = (const float*)d_in[7];
  const float* dt_w   = (const float*)d_in[8];
  const float* dt_b   = (const float*)d_in[9];
  const float* A_log  = (const float*)d_in[10];
  const float* Dp     = (const float*)d_in[11];
  const float* out_w  = (const float*)d_in[12];
  const float* c1w    = (const float*)d_in[13];
  const float* c1b    = (const float*)d_in[14];
  const float* c2w    = (const float*)d_in[15];
  const float* c2b    = (const float*)d_in[16];
  const float* c3w    = (const float*)d_in[17];
  const float* c3b    = (const float*)d_in[18];
  const float* fcw    = (const float*)d_in[19];
  const float* fcb    = (const float*)d_in[20];
  float* out = (float*)d_out;

  // workspace: ~13.6M floats = 55 MB
  float* ws = (float*)d_ws;
  float* f0     = ws;                 // 5,120,000
  float* f1     = f0 + 5120000;       // 5,120,000
  float* Sc     = f1 + 5120000;       // 1,638,400 (B*NCH*256)
  float* Pc     = Sc + 1638400;       // 1,638,400
  float* pooled = Pc + 1638400;       // 8,192
  short* wt1b   = (short*)(pooled + 8192);  // 2,048 shorts
  short* wt2b   = wt1b + 2048;              // 12,288 shorts
  short* wt3b   = wt2b + 12288;             // 12,288 shorts

  k_wt<<<104,256,0,stream>>>(c1w, c2w, c3w, wt1b, wt2b, wt3b);
  k_embed<<<2500,256,0,stream>>>(x, idx, embed, f0);
  for (int l=0;l<NL;l++){
    const float* fin = (l & 1) ? f1 : f0;
    float*       fo  = (l & 1) ? f0 : f1;
    k_l1<<<dim3(NCH,B),256,0,stream>>>(fin, norm_w + l*8, in_proj + l*256, conv_w + l*48,
         conv_b + l*16, x_proj + l*528, dt_w + l*16, dt_b + l*16, A_log + l*256, Sc, Pc);
    k_l3<<<dim3(NCH,B),256,0,stream>>>(fin, fo, norm_w + l*8, in_proj + l*256, conv_w + l*48,
         conv_b + l*16, x_proj + l*528, dt_w + l*16, dt_b + l*16, A_log + l*256,
         Dp + l*16, Sc, Pc, out_w + l*128);
  }
  (void)hipMemsetAsync(pooled, 0, B*64*sizeof(float), stream);
  k_head<<<dim3(79,B),256,0,stream>>>(f0, wt1b, c1b, wt2b, c2b, wt3b, c3b, pooled);
  k_fc<<<(B*230+255)/256,256,0,stream>>>(pooled, fcw, fcb, out);
}

// Round 10
// 1335.172 us; speedup vs baseline: 8.6360x; 1.2769x over previous
//
#include <hip/hip_runtime.h>
#include <math.h>

#define B 128
#define L 5000
#define NL 4
#define NCH 50
#define LC 100
#define ST 50
#define HT 64

typedef __attribute__((ext_vector_type(8))) short bf16x8;
typedef __attribute__((ext_vector_type(4))) short short4v;
typedef __attribute__((ext_vector_type(4))) float f32x4;

__device__ __forceinline__ float sigmoidf_(float x){ return 1.f/(1.f+__expf(-x)); }
__device__ __forceinline__ float siluf_(float x){ return x*sigmoidf_(x); }
__device__ __forceinline__ float softplusf_(float x){ return fmaxf(x,0.f) + log1pf(__expf(-fabsf(x))); }
__device__ __forceinline__ short bfc_(float x){
  union { float f; unsigned u; } v; v.f = x;
  unsigned r = v.u + 0x7fffu + ((v.u >> 16) & 1u);
  return (short)(r >> 16);
}
__device__ __forceinline__ float b2f_(short s){
  union { unsigned u; float f; } v; v.u = ((unsigned)(unsigned short)s) << 16;
  return v.f;
}
#define SW(row, col) (((row)<<6) + ((col) ^ (((row)&7)<<3)))

// ---------------- f0 = embed[idx] * x ----------------
__global__ void k_embed(const float* __restrict__ x, const int* __restrict__ idx,
                        const float* __restrict__ embed, float* __restrict__ f){
  int gid = blockIdx.x*256 + threadIdx.x;
  if (gid >= B*L) return;
  int t = gid % L;
  float xv = x[gid];
  const float* er = embed + (size_t)idx[t]*8;
  float4 e0 = *(const float4*)(er);
  float4 e1 = *(const float4*)(er+4);
  *(float4*)(f + (size_t)gid*8)   = make_float4(e0.x*xv, e0.y*xv, e0.z*xv, e0.w*xv);
  *(float4*)(f + (size_t)gid*8+4) = make_float4(e1.x*xv, e1.y*xv, e1.z*xv, e1.w*xv);
}

// ---------------- fused layer pass 1: preprocess + per-chunk scan -> Sc, Pc ----------------
__global__ __launch_bounds__(256,4) void k_l1(const float* __restrict__ fin,
    const float* __restrict__ norm_w, const float* __restrict__ in_proj,
    const float* __restrict__ conv_w, const float* __restrict__ conv_b,
    const float* __restrict__ x_proj, const float* __restrict__ dt_w,
    const float* __restrict__ dt_b, const float* __restrict__ A_log,
    float* __restrict__ Sc, float* __restrict__ Pc){
  __shared__ float fsub[52][8], rn[52];
  __shared__ float uL[ST][17];
  __shared__ float2 duL[ST][16];
  __shared__ float BLs[ST][17];
  __shared__ float dbc0[ST];
  int tid = threadIdx.x, ch = blockIdx.x, b = blockIdx.y;
  int e = tid>>4, n = tid&15;
  int ct = tid&15;
  float ipnw_c[8], cwc[3];
  #pragma unroll
  for (int d=0;d<8;d++) ipnw_c[d] = in_proj[ct*8+d]*norm_w[d];
  #pragma unroll
  for (int k=0;k<3;k++) cwc[k] = conv_w[ct*3+k];
  float cbc = conv_b[ct];
  float xp0_c = x_proj[ct];
  float xpB_r[16];
  #pragma unroll
  for (int k=0;k<16;k++) xpB_r[k] = x_proj[(1+ct)*16+k];
  float dtw_e = dt_w[ct], dtb_e = dt_b[ct];
  float a = -__expf(A_log[e*16+n]);
  float h = 0.f, dsum = 0.f;
  int t00 = ch*LC;
  for (int sub=0; sub<LC/ST; sub++){
    int ts = t00 + sub*ST;
    __syncthreads();
    for (int i=tid;i<104;i+=256){ int r=i>>1, half=i&1; int t=ts-2+r;
      *(float4*)&fsub[r][half*4] = (t>=0) ? *(const float4*)&fin[((size_t)b*L+t)*8+half*4]
                                          : make_float4(0.f,0.f,0.f,0.f); }
    __syncthreads();
    if (tid < 52){ float ss=0.f;
      #pragma unroll
      for (int d=0;d<8;d++){ float v=fsub[tid][d]; ss += v*v; }
      rn[tid] = rsqrtf(ss*0.125f + 1e-5f); }
    __syncthreads();
    for (int i=tid;i<ST*16;i+=256){ int j=i>>4;
      float acc = cbc;
      #pragma unroll
      for (int kk=0;kk<3;kk++){
        int r = j + kk;
        float dot=0.f;
        #pragma unroll
        for (int d=0;d<8;d++) dot += ipnw_c[d]*fsub[r][d];
        acc += cwc[kk]*(dot*rn[r]);
      }
      float uv = siluf_(acc);
      uL[j][ct] = uv;
      float pp = xp0_c*uv;
      pp += __shfl_xor(pp, 1, 64);
      pp += __shfl_xor(pp, 2, 64);
      pp += __shfl_xor(pp, 4, 64);
      pp += __shfl_xor(pp, 8, 64);
      if (ct == 0) dbc0[j] = pp;
    }
    __syncthreads();
    for (int i=tid;i<ST*16;i+=256){ int j=i>>4;
      float accB=0.f;
      #pragma unroll
      for (int c=0;c<16;c++) accB += xpB_r[c]*uL[j][c];
      BLs[j][ct] = accB;
      float dd = softplusf_(dbc0[j]*dtw_e + dtb_e);
      duL[j][ct] = make_float2(dd, dd*uL[j][ct]);
    }
    __syncthreads();
    for (int j=0;j<ST;j++){
      float2 du = duL[j][e];
      float bb = BLs[j][n];
      h = __expf(du.x*a)*h + du.y*bb;
      dsum += du.x;
    }
  }
  size_t o = ((size_t)b*NCH + ch)*256 + tid;
  Sc[o] = h;
  Pc[o] = __expf(a*dsum);
}

// ---------------- fused layer pass 3: h0 prefix + preprocess + scan + gated out_proj ----------------
__global__ __launch_bounds__(256,4) void k_l3(const float* __restrict__ fin, float* __restrict__ fout,
    const float* __restrict__ norm_w, const float* __restrict__ in_proj,
    const float* __restrict__ conv_w, const float* __restrict__ conv_b,
    const float* __restrict__ x_proj, const float* __restrict__ dt_w,
    const float* __restrict__ dt_b, const float* __restrict__ A_log,
    const float* __restrict__ Dp, const float* __restrict__ Sc,
    const float* __restrict__ Pc, const float* __restrict__ ow){
  __shared__ float fsub[52][8], rn[52];
  __shared__ float uL[ST][17], szL[ST][17], yL[ST][17];
  __shared__ float2 duL[ST][16], BCL[ST][16];
  __shared__ float dbc0[ST];
  __shared__ float s_owp[8*17], s_De[16];
  __shared__ float hcL[10*256];     // p-values for 10 scan steps (deferred reduce)
  int tid = threadIdx.x, ch = blockIdx.x, b = blockIdx.y;
  int e = tid>>4, n = tid&15;
  int ct = tid&15;
  int dt8 = tid&7;
  float ipnw_c[8], ipnwz_c[8], cwc[3];
  #pragma unroll
  for (int d=0;d<8;d++){
    ipnw_c[d]  = in_proj[ct*8+d]*norm_w[d];
    ipnwz_c[d] = in_proj[(16+ct)*8+d]*norm_w[d];
  }
  #pragma unroll
  for (int k=0;k<3;k++) cwc[k] = conv_w[ct*3+k];
  float cbc = conv_b[ct];
  float xp0_c = x_proj[ct];
  float xpB_r[16], xpC_r[16];
  #pragma unroll
  for (int k=0;k<16;k++){
    xpB_r[k] = x_proj[(1+ct)*16+k];
    xpC_r[k] = x_proj[(17+ct)*16+k];
  }
  float dtw_e = dt_w[ct], dtb_e = dt_b[ct];
  float a = -__expf(A_log[e*16+n]);
  if (tid < 128) s_owp[(tid>>4)*17 + (tid&15)] = ow[tid];
  if (tid < 16) s_De[tid] = Dp[tid];
  float h = 0.f;
  for (int c2=0; c2<ch; c2++){
    size_t o = ((size_t)b*NCH + c2)*256 + tid;
    h = Pc[o]*h + Sc[o];
  }
  int t00 = ch*LC;
  for (int sub=0; sub<LC/ST; sub++){
    int ts = t00 + sub*ST;
    __syncthreads();
    for (int i=tid;i<104;i+=256){ int r=i>>1, half=i&1; int t=ts-2+r;
      *(float4*)&fsub[r][half*4] = (t>=0) ? *(const float4*)&fin[((size_t)b*L+t)*8+half*4]
                                          : make_float4(0.f,0.f,0.f,0.f); }
    __syncthreads();
    if (tid < 52){ float ss=0.f;
      #pragma unroll
      for (int d=0;d<8;d++){ float v=fsub[tid][d]; ss += v*v; }
      rn[tid] = rsqrtf(ss*0.125f + 1e-5f); }
    __syncthreads();
    // u + sz phase + dbc0
    for (int i=tid;i<ST*16;i+=256){ int j=i>>4;
      float acc = cbc;
      #pragma unroll
      for (int kk=0;kk<3;kk++){
        int r = j + kk;
        float dot=0.f;
        #pragma unroll
        for (int d=0;d<8;d++) dot += ipnw_c[d]*fsub[r][d];
        acc += cwc[kk]*(dot*rn[r]);
      }
      float uv = siluf_(acc);
      uL[j][ct] = uv;
      int r2 = j + 2;
      float dz=0.f;
      #pragma unroll
      for (int d=0;d<8;d++) dz += ipnwz_c[d]*fsub[r2][d];
      szL[j][ct] = siluf_(dz*rn[r2]);
      float pp = xp0_c*uv;
      pp += __shfl_xor(pp, 1, 64);
      pp += __shfl_xor(pp, 2, 64);
      pp += __shfl_xor(pp, 4, 64);
      pp += __shfl_xor(pp, 8, 64);
      if (ct == 0) dbc0[j] = pp;
    }
    __syncthreads();
    // BC + dl phase
    for (int i=tid;i<ST*16;i+=256){ int j=i>>4;
      float accB=0.f, accC=0.f;
      #pragma unroll
      for (int c=0;c<16;c++){
        float uv = uL[j][c];
        accB += xpB_r[c]*uv;
        accC += xpC_r[c]*uv;
      }
      BCL[j][ct] = make_float2(accB, accC);
      float dd = softplusf_(dbc0[j]*dtw_e + dtb_e);
      duL[j][ct] = make_float2(dd, dd*uL[j][ct]);
    }
    __syncthreads();
    // scan: no cross-lane ops in the serial loop; p stored to LDS, reduced every 10 steps
    for (int q=0; q<ST/10; q++){
      #pragma unroll
      for (int j2=0; j2<10; j2++){
        int j = q*10 + j2;
        float2 du = duL[j][e];
        float2 bc = BCL[j][n];
        h = __expf(du.x*a)*h + du.y*bc.x;
        hcL[j2*256 + tid] = h*bc.y;
      }
      __syncthreads();
      if (tid < 160){
        int jj = tid>>4, ee = tid&15;
        const float4* hp = (const float4*)&hcL[jj*256 + ee*16];
        float4 p0 = hp[0], p1 = hp[1], p2 = hp[2], p3 = hp[3];
        float s = ((p0.x+p0.y)+(p0.z+p0.w)) + ((p1.x+p1.y)+(p1.z+p1.w))
                + ((p2.x+p2.y)+(p2.z+p2.w)) + ((p3.x+p3.y)+(p3.z+p3.w));
        yL[q*10 + jj][ee] = s;
      }
      __syncthreads();
    }
    // out_proj + residual (D*u folded in here)
    for (int i=tid;i<ST*8;i+=256){ int j=i>>3;
      size_t fi = ((size_t)b*L + ts + j)*8 + dt8;
      float acc = fsub[j+2][dt8];
      #pragma unroll
      for (int e2=0;e2<16;e2++){
        float ye = yL[j][e2] + s_De[e2]*uL[j][e2];
        acc += s_owp[dt8*17+e2]*ye*szL[j][e2];
      }
      fout[fi] = acc;
    }
  }
}

// ---------------- head weight prep ----------------
__global__ void k_wt(const float* __restrict__ c1w, const float* __restrict__ c2w,
                     const float* __restrict__ c3w, short* __restrict__ wt1b,
                     short* __restrict__ wt2b, short* __restrict__ wt3b){
  int idx = blockIdx.x*256 + threadIdx.x;
  if (idx < 2048){
    int c = idx >> 5, m = idx & 31;
    int kk = m >> 3, d = m & 7;
    wt1b[idx] = (kk < 3) ? bfc_(c1w[c*24 + d*3 + kk]) : (short)0;
  } else if (idx < 2048 + 12288){
    int i = idx - 2048;
    int c = i / 192, rem = i % 192;
    int k = rem >> 6, ci = rem & 63;
    wt2b[i] = bfc_(c2w[c*192 + ci*3 + k]);
  } else if (idx < 2048 + 24576){
    int i = idx - 2048 - 12288;
    int c = i / 192, rem = i % 192;
    int k = rem >> 6, ci = rem & 63;
    wt3b[i] = bfc_(c3w[c*192 + ci*3 + k]);
  }
}

// ---------------- fused head: all three convs via bf16 MFMA ----------------
__global__ __launch_bounds__(256) void k_head(const float* __restrict__ f,
   const short* __restrict__ wt1b, const float* __restrict__ c1b,
   const short* __restrict__ wt2b, const float* __restrict__ c2b,
   const short* __restrict__ wt3b, const float* __restrict__ c3b,
   float* __restrict__ pooled){
  __shared__ short fs_b[84*8];
  __shared__ short h1t[84*64];
  __shared__ short h2t[66*64];
  int tid  = threadIdx.x;
  int b    = blockIdx.y;
  int t0   = blockIdx.x * HT;
  int lane = tid & 63;
  int w    = tid >> 6;
  int cb   = w*16;
  int lc   = lane & 15, g = lane >> 4;

  for (int task = tid; task < 672; task += 256){
    int r = task >> 3, d = task & 7;
    int t = t0 - 3 + r;
    float v = (r < 70 && t >= 0 && t < L) ? f[((size_t)b*L + t)*8 + d] : 0.f;
    fs_b[task] = bfc_(v);
  }
  __syncthreads();

  {
    bf16x8 a1 = *(const bf16x8*)(wt1b + (cb + lc)*32 + g*8);
    f32x4 bias1 = *(const f32x4*)(c1b + cb + (g<<2));
    #pragma unroll
    for (int nt=0; nt<5; nt++){
      int tcol = nt*16 + lc;
      bf16x8 bv = {0,0,0,0,0,0,0,0};
      if (g < 3) bv = *(bf16x8*)&fs_b[(tcol+g)*8];
      f32x4 acc = {0.f,0.f,0.f,0.f};
      acc = __builtin_amdgcn_mfma_f32_16x16x32_bf16(a1, bv, acc, 0, 0, 0);
      if (tcol < 68){
        int t1 = t0 - 2 + tcol;
        bool v = (t1 >= 0 && t1 < L);
        short4v pk;
        #pragma unroll
        for (int reg=0;reg<4;reg++)
          pk[reg] = bfc_(v ? fmaxf(acc[reg] + bias1[reg], 0.f) : 0.f);
        *(short4v*)&h1t[SW(tcol, cb + (g<<2))] = pk;
      }
    }
  }
  __syncthreads();

  {
    const short* wA = wt2b + (cb + lc)*192 + g*8;
    bf16x8 a2[6];
    #pragma unroll
    for (int s=0;s<6;s++) a2[s] = *(const bf16x8*)(wA + 32*s);
    f32x4 bias2 = *(const f32x4*)(c2b + cb + (g<<2));
    #pragma unroll
    for (int nt=0; nt<5; nt++){
      f32x4 acc = {0.f,0.f,0.f,0.f};
      #pragma unroll
      for (int s=0;s<6;s++){
        int k = s>>1, ci0 = (s&1)*32;
        int jr = nt*16 + lc + k;
        bf16x8 bfr = *(bf16x8*)&h1t[SW(jr, ci0 + g*8)];
        acc = __builtin_amdgcn_mfma_f32_16x16x32_bf16(a2[s], bfr, acc, 0, 0, 0);
      }
      int tr = nt*16 + lc;
      if (tr < 66){
        int tg = t0 - 1 + tr;
        bool v = (tg >= 0 && tg < L);
        short4v pk;
        #pragma unroll
        for (int reg=0;reg<4;reg++)
          pk[reg] = bfc_(v ? fmaxf(acc[reg] + bias2[reg], 0.f) : 0.f);
        *(short4v*)&h2t[SW(tr, cb + (g<<2))] = pk;
      }
    }
  }
  __syncthreads();

  {
    const short* wA = wt3b + (cb + lc)*192 + g*8;
    bf16x8 a3[6];
    #pragma unroll
    for (int s=0;s<6;s++) a3[s] = *(const bf16x8*)(wA + 32*s);
    f32x4 bias3 = *(const f32x4*)(c3b + cb + (g<<2));
    int c0 = cb + (g<<2);
    float pool[4] = {0.f,0.f,0.f,0.f};
    #pragma unroll
    for (int nt=0; nt<4; nt++){
      f32x4 acc = {0.f,0.f,0.f,0.f};
      #pragma unroll
      for (int s=0;s<6;s++){
        int k = s>>1, ci0 = (s&1)*32;
        int jr = nt*16 + lc + k;
        bf16x8 bfr = *(bf16x8*)&h2t[SW(jr, ci0 + g*8)];
        acc = __builtin_amdgcn_mfma_f32_16x16x32_bf16(a3[s], bfr, acc, 0, 0, 0);
      }
      int t = t0 + nt*16 + lc;
      short4v hres = *(short4v*)&h1t[SW(nt*16 + lc + 2, c0)];
      if (t < L){
        #pragma unroll
        for (int reg=0;reg<4;reg++)
          pool[reg] += fmaxf(b2f_(hres[reg]) + acc[reg] + bias3[reg], 0.f);
      }
    }
    #pragma unroll
    for (int m=1; m<16; m<<=1){
      #pragma unroll
      for (int reg=0;reg<4;reg++) pool[reg] += __shfl_xor(pool[reg], m, 64);
    }
    if (lc == 0){
      #pragma unroll
      for (int reg=0;reg<4;reg++) atomicAdd(&pooled[b*64 + c0 + reg], pool[reg]);
    }
  }
}

// ---------------- final FC ----------------
__global__ void k_fc(const float* __restrict__ pooled, const float* __restrict__ fcw,
                     const float* __restrict__ fcb, float* __restrict__ out){
  int gid = blockIdx.x*256 + threadIdx.x;
  if (gid >= B*230) return;
  int b = gid / 230, j = gid % 230;
  const float* p = pooled + b*64;
  const float* wv = fcw + j*64;
  float a = 0.f;
  #pragma unroll
  for (int c=0;c<64;c++) a += p[c]*wv[c];
  out[gid] = a*(1.f/(float)L) + fcb[j];
}

extern "C" void kernel_launch(void* const* d_in, const int* in_sizes, int n_in,
                              void* d_out, int out_size, void* d_ws, size_t ws_size,
                              hipStream_t stream){
  const float* x      = (const float*)d_in[0];
  const int*   idx    = (const int*)  d_in[1];
  const float* embed  = (const float*)d_in[2];
  const float* norm_w = (const float*)d_in[3];
  const float* in_proj= (const float*)d_in[4];
  const float* conv_w = (const float*)d_in[5];
  const float* conv_b = (const float*)d_in[6];
  const float* x_proj = (const float*)d_in[7];
  const float* dt_w   = (const float*)d_in[8];
  const float* dt_b   = (const float*)d_in[9];
  const float* A_log  = (const float*)d_in[10];
  const float* Dp     = (const float*)d_in[11];
  const float* out_w  = (const float*)d_in[12];
  const float* c1w    = (const float*)d_in[13];
  const float* c1b    = (const float*)d_in[14];
  const float* c2w    = (const float*)d_in[15];
  const float* c2b    = (const float*)d_in[16];
  const float* c3w    = (const float*)d_in[17];
  const float* c3b    = (const float*)d_in[18];
  const float* fcw    = (const float*)d_in[19];
  const float* fcb    = (const float*)d_in[20];
  float* out = (float*)d_out;

  // workspace: ~13.6M floats = 55 MB
  float* ws = (float*)d_ws;
  float* f0     = ws;                 // 5,120,000
  float* f1     = f0 + 5120000;       // 5,120,000
  float* Sc     = f1 + 5120000;       // 1,638,400 (B*NCH*256)
  float* Pc     = Sc + 1638400;       // 1,638,400
  float* pooled = Pc + 1638400;       // 8,192
  short* wt1b   = (short*)(pooled + 8192);  // 2,048 shorts
  short* wt2b   = wt1b + 2048;              // 12,288 shorts
  short* wt3b   = wt2b + 12288;             // 12,288 shorts

  k_wt<<<104,256,0,stream>>>(c1w, c2w, c3w, wt1b, wt2b, wt3b);
  k_embed<<<2500,256,0,stream>>>(x, idx, embed, f0);
  for (int l=0;l<NL;l++){
    const float* fin = (l & 1) ? f1 : f0;
    float*       fo  = (l & 1) ? f0 : f1;
    k_l1<<<dim3(NCH,B),256,0,stream>>>(fin, norm_w + l*8, in_proj + l*256, conv_w + l*48,
         conv_b + l*16, x_proj + l*528, dt_w + l*16, dt_b + l*16, A_log + l*256, Sc, Pc);
    k_l3<<<dim3(NCH,B),256,0,stream>>>(fin, fo, norm_w + l*8, in_proj + l*256, conv_w + l*48,
         conv_b + l*16, x_proj + l*528, dt_w + l*16, dt_b + l*16, A_log + l*256,
         Dp + l*16, Sc, Pc, out_w + l*128);
  }
  (void)hipMemsetAsync(pooled, 0, B*64*sizeof(float), stream);
  k_head<<<dim3(79,B),256,0,stream>>>(f0, wt1b, c1b, wt2b, c2b, wt3b, c3b, pooled);
  k_fc<<<(B*230+255)/256,256,0,stream>>>(pooled, fcw, fcb, out);
}

// Round 11
// 1217.166 us; speedup vs baseline: 9.4733x; 1.0970x over previous
//
#include <hip/hip_runtime.h>
#include <math.h>

#define B 128
#define L 5000
#define NL 4
#define NCH 50
#define LC 100
#define ST 50
#define HT 128

typedef __attribute__((ext_vector_type(8))) short bf16x8;
typedef __attribute__((ext_vector_type(4))) short short4v;
typedef __attribute__((ext_vector_type(4))) float f32x4;

__device__ __forceinline__ float sigmoidf_(float x){ return 1.f/(1.f+__expf(-x)); }
__device__ __forceinline__ float siluf_(float x){ return x*sigmoidf_(x); }
__device__ __forceinline__ float softplusf_(float x){ return fmaxf(x,0.f) + log1pf(__expf(-fabsf(x))); }
__device__ __forceinline__ short bfc_(float x){
  union { float f; unsigned u; } v; v.f = x;
  unsigned r = v.u + 0x7fffu + ((v.u >> 16) & 1u);
  return (short)(r >> 16);
}
__device__ __forceinline__ float b2f_(short s){
  union { unsigned u; float f; } v; v.u = ((unsigned)(unsigned short)s) << 16;
  return v.f;
}
#define SW(row, col) (((row)<<6) + ((col) ^ (((row)&7)<<3)))

// ---------------- f0 = embed[idx] * x ----------------
__global__ void k_embed(const float* __restrict__ x, const int* __restrict__ idx,
                        const float* __restrict__ embed, float* __restrict__ f){
  int gid = blockIdx.x*256 + threadIdx.x;
  if (gid >= B*L) return;
  int t = gid % L;
  float xv = x[gid];
  const float* er = embed + (size_t)idx[t]*8;
  float4 e0 = *(const float4*)(er);
  float4 e1 = *(const float4*)(er+4);
  *(float4*)(f + (size_t)gid*8)   = make_float4(e0.x*xv, e0.y*xv, e0.z*xv, e0.w*xv);
  *(float4*)(f + (size_t)gid*8+4) = make_float4(e1.x*xv, e1.y*xv, e1.z*xv, e1.w*xv);
}

// ---------------- fused layer pass 1 (unchanged from r10) ----------------
__global__ __launch_bounds__(256,4) void k_l1(const float* __restrict__ fin,
    const float* __restrict__ norm_w, const float* __restrict__ in_proj,
    const float* __restrict__ conv_w, const float* __restrict__ conv_b,
    const float* __restrict__ x_proj, const float* __restrict__ dt_w,
    const float* __restrict__ dt_b, const float* __restrict__ A_log,
    float* __restrict__ Sc, float* __restrict__ Pc){
  __shared__ float fsub[52][8], rn[52];
  __shared__ float uL[ST][17];
  __shared__ float2 duL[ST][16];
  __shared__ float BLs[ST][17];
  __shared__ float dbc0[ST];
  int tid = threadIdx.x, ch = blockIdx.x, b = blockIdx.y;
  int e = tid>>4, n = tid&15;
  int ct = tid&15;
  float ipnw_c[8], cwc[3];
  #pragma unroll
  for (int d=0;d<8;d++) ipnw_c[d] = in_proj[ct*8+d]*norm_w[d];
  #pragma unroll
  for (int k=0;k<3;k++) cwc[k] = conv_w[ct*3+k];
  float cbc = conv_b[ct];
  float xp0_c = x_proj[ct];
  float xpB_r[16];
  #pragma unroll
  for (int k=0;k<16;k++) xpB_r[k] = x_proj[(1+ct)*16+k];
  float dtw_e = dt_w[ct], dtb_e = dt_b[ct];
  float a = -__expf(A_log[e*16+n]);
  float h = 0.f, dsum = 0.f;
  int t00 = ch*LC;
  for (int sub=0; sub<LC/ST; sub++){
    int ts = t00 + sub*ST;
    __syncthreads();
    for (int i=tid;i<104;i+=256){ int r=i>>1, half=i&1; int t=ts-2+r;
      *(float4*)&fsub[r][half*4] = (t>=0) ? *(const float4*)&fin[((size_t)b*L+t)*8+half*4]
                                          : make_float4(0.f,0.f,0.f,0.f); }
    __syncthreads();
    if (tid < 52){ float ss=0.f;
      #pragma unroll
      for (int d=0;d<8;d++){ float v=fsub[tid][d]; ss += v*v; }
      rn[tid] = rsqrtf(ss*0.125f + 1e-5f); }
    __syncthreads();
    for (int i=tid;i<ST*16;i+=256){ int j=i>>4;
      float acc = cbc;
      #pragma unroll
      for (int kk=0;kk<3;kk++){
        int r = j + kk;
        float dot=0.f;
        #pragma unroll
        for (int d=0;d<8;d++) dot += ipnw_c[d]*fsub[r][d];
        acc += cwc[kk]*(dot*rn[r]);
      }
      float uv = siluf_(acc);
      uL[j][ct] = uv;
      float pp = xp0_c*uv;
      pp += __shfl_xor(pp, 1, 64);
      pp += __shfl_xor(pp, 2, 64);
      pp += __shfl_xor(pp, 4, 64);
      pp += __shfl_xor(pp, 8, 64);
      if (ct == 0) dbc0[j] = pp;
    }
    __syncthreads();
    for (int i=tid;i<ST*16;i+=256){ int j=i>>4;
      float accB=0.f;
      #pragma unroll
      for (int c=0;c<16;c++) accB += xpB_r[c]*uL[j][c];
      BLs[j][ct] = accB;
      float dd = softplusf_(dbc0[j]*dtw_e + dtb_e);
      duL[j][ct] = make_float2(dd, dd*uL[j][ct]);
    }
    __syncthreads();
    for (int j=0;j<ST;j++){
      float2 du = duL[j][e];
      float bb = BLs[j][n];
      h = __expf(du.x*a)*h + du.y*bb;
      dsum += du.x;
    }
  }
  size_t o = ((size_t)b*NCH + ch)*256 + tid;
  Sc[o] = h;
  Pc[o] = __expf(a*dsum);
}

// ---------------- fused layer pass 3: conflict-free deferred reduce + folded gating ----------------
__global__ __launch_bounds__(256,4) void k_l3(const float* __restrict__ fin, float* __restrict__ fout,
    const float* __restrict__ norm_w, const float* __restrict__ in_proj,
    const float* __restrict__ conv_w, const float* __restrict__ conv_b,
    const float* __restrict__ x_proj, const float* __restrict__ dt_w,
    const float* __restrict__ dt_b, const float* __restrict__ A_log,
    const float* __restrict__ Dp, const float* __restrict__ Sc,
    const float* __restrict__ Pc, const float* __restrict__ ow){
  __shared__ float fsub[52][8], rn[52];
  __shared__ float uL[ST*16], szL[ST*16], yL[ST*16];   // stride-16 flat rows
  __shared__ float2 duL[ST*16], BCL[ST*16];
  __shared__ float dbc0[ST];
  __shared__ float s_owp[8*17], s_De[16];
  __shared__ float hcL[10*320];                        // [j2][e*20+n]
  int tid = threadIdx.x, ch = blockIdx.x, b = blockIdx.y;
  int e = tid>>4, n = tid&15;
  int ct = tid&15;
  int dt8 = tid&7;
  float ipnw_c[8], ipnwz_c[8], cwc[3];
  #pragma unroll
  for (int d=0;d<8;d++){
    ipnw_c[d]  = in_proj[ct*8+d]*norm_w[d];
    ipnwz_c[d] = in_proj[(16+ct)*8+d]*norm_w[d];
  }
  #pragma unroll
  for (int k=0;k<3;k++) cwc[k] = conv_w[ct*3+k];
  float cbc = conv_b[ct];
  float xp0_c = x_proj[ct];
  float xpB_r[16], xpC_r[16];
  #pragma unroll
  for (int k=0;k<16;k++){
    xpB_r[k] = x_proj[(1+ct)*16+k];
    xpC_r[k] = x_proj[(17+ct)*16+k];
  }
  float dtw_e = dt_w[ct], dtb_e = dt_b[ct];
  float a = -__expf(A_log[e*16+n]);
  if (tid < 128) s_owp[(tid>>4)*17 + (tid&15)] = ow[tid];
  if (tid < 16) s_De[tid] = Dp[tid];
  float h = 0.f;
  for (int c2=0; c2<ch; c2++){
    size_t o = ((size_t)b*NCH + c2)*256 + tid;
    h = Pc[o]*h + Sc[o];
  }
  int t00 = ch*LC;
  for (int sub=0; sub<LC/ST; sub++){
    int ts = t00 + sub*ST;
    __syncthreads();
    for (int i=tid;i<104;i+=256){ int r=i>>1, half=i&1; int t=ts-2+r;
      *(float4*)&fsub[r][half*4] = (t>=0) ? *(const float4*)&fin[((size_t)b*L+t)*8+half*4]
                                          : make_float4(0.f,0.f,0.f,0.f); }
    __syncthreads();
    if (tid < 52){ float ss=0.f;
      #pragma unroll
      for (int d=0;d<8;d++){ float v=fsub[tid][d]; ss += v*v; }
      rn[tid] = rsqrtf(ss*0.125f + 1e-5f); }
    __syncthreads();
    // u + sz phase + dbc0
    for (int i=tid;i<ST*16;i+=256){ int j=i>>4;
      float acc = cbc;
      #pragma unroll
      for (int kk=0;kk<3;kk++){
        int r = j + kk;
        float dot=0.f;
        #pragma unroll
        for (int d=0;d<8;d++) dot += ipnw_c[d]*fsub[r][d];
        acc += cwc[kk]*(dot*rn[r]);
      }
      float uv = siluf_(acc);
      uL[j*16+ct] = uv;
      int r2 = j + 2;
      float dz=0.f;
      #pragma unroll
      for (int d=0;d<8;d++) dz += ipnwz_c[d]*fsub[r2][d];
      szL[j*16+ct] = siluf_(dz*rn[r2]);
      float pp = xp0_c*uv;
      pp += __shfl_xor(pp, 1, 64);
      pp += __shfl_xor(pp, 2, 64);
      pp += __shfl_xor(pp, 4, 64);
      pp += __shfl_xor(pp, 8, 64);
      if (ct == 0) dbc0[j] = pp;
    }
    __syncthreads();
    // BC + dl phase (b128 row reads of u)
    for (int i=tid;i<ST*16;i+=256){ int j=i>>4;
      f32x4 u0 = *(const f32x4*)&uL[j*16];
      f32x4 u1 = *(const f32x4*)&uL[j*16+4];
      f32x4 u2 = *(const f32x4*)&uL[j*16+8];
      f32x4 u3 = *(const f32x4*)&uL[j*16+12];
      float accB=0.f, accC=0.f;
      #pragma unroll
      for (int c=0;c<4;c++){
        accB += xpB_r[c]*u0[c] + xpB_r[4+c]*u1[c] + xpB_r[8+c]*u2[c] + xpB_r[12+c]*u3[c];
        accC += xpC_r[c]*u0[c] + xpC_r[4+c]*u1[c] + xpC_r[8+c]*u2[c] + xpC_r[12+c]*u3[c];
      }
      BCL[j*16+ct] = make_float2(accB, accC);
      float dd = softplusf_(dbc0[j]*dtw_e + dtb_e);
      duL[j*16+ct] = make_float2(dd, dd*uL[j*16+ct]);
    }
    __syncthreads();
    // scan: serial loop free of cross-lane ops; reduce every 10 steps (conflict-free layout)
    for (int q=0; q<ST/10; q++){
      #pragma unroll
      for (int j2=0; j2<10; j2++){
        int j = q*10 + j2;
        float2 du = duL[j*16+e];
        float2 bc = BCL[j*16+n];
        h = __expf(du.x*a)*h + du.y*bc.x;
        hcL[j2*320 + e*20 + n] = h*bc.y;
      }
      __syncthreads();
      if (tid < 160){
        int jj = tid>>4, ee = tid&15;
        int j = q*10 + jj;
        const f32x4* hp = (const f32x4*)&hcL[jj*320 + ee*20];
        f32x4 p0 = hp[0], p1 = hp[1], p2 = hp[2], p3 = hp[3];
        float s = ((p0[0]+p0[1])+(p0[2]+p0[3])) + ((p1[0]+p1[1])+(p1[2]+p1[3]))
                + ((p2[0]+p2[1])+(p2[2]+p2[3])) + ((p3[0]+p3[1])+(p3[2]+p3[3]));
        // fold D*u and silu(z) gating here
        yL[j*16+ee] = (s + s_De[ee]*uL[j*16+ee]) * szL[j*16+ee];
      }
      __syncthreads();
    }
    // out_proj + residual
    for (int i=tid;i<ST*8;i+=256){ int j=i>>3;
      size_t fi = ((size_t)b*L + ts + j)*8 + dt8;
      float acc = fsub[j+2][dt8];
      f32x4 y0 = *(const f32x4*)&yL[j*16];
      f32x4 y1 = *(const f32x4*)&yL[j*16+4];
      f32x4 y2 = *(const f32x4*)&yL[j*16+8];
      f32x4 y3 = *(const f32x4*)&yL[j*16+12];
      #pragma unroll
      for (int c=0;c<4;c++)
        acc += s_owp[dt8*17+c]*y0[c] + s_owp[dt8*17+4+c]*y1[c]
             + s_owp[dt8*17+8+c]*y2[c] + s_owp[dt8*17+12+c]*y3[c];
      fout[fi] = acc;
    }
  }
}

// ---------------- head weight prep ----------------
__global__ void k_wt(const float* __restrict__ c1w, const float* __restrict__ c2w,
                     const float* __restrict__ c3w, short* __restrict__ wt1b,
                     short* __restrict__ wt2b, short* __restrict__ wt3b){
  int idx = blockIdx.x*256 + threadIdx.x;
  if (idx < 2048){
    int c = idx >> 5, m = idx & 31;
    int kk = m >> 3, d = m & 7;
    wt1b[idx] = (kk < 3) ? bfc_(c1w[c*24 + d*3 + kk]) : (short)0;
  } else if (idx < 2048 + 12288){
    int i = idx - 2048;
    int c = i / 192, rem = i % 192;
    int k = rem >> 6, ci = rem & 63;
    wt2b[i] = bfc_(c2w[c*192 + ci*3 + k]);
  } else if (idx < 2048 + 24576){
    int i = idx - 2048 - 12288;
    int c = i / 192, rem = i % 192;
    int k = rem >> 6, ci = rem & 63;
    wt3b[i] = bfc_(c3w[c*192 + ci*3 + k]);
  }
}

// ---------------- fused head, HT=128 tile ----------------
__global__ __launch_bounds__(256) void k_head(const float* __restrict__ f,
   const short* __restrict__ wt1b, const float* __restrict__ c1b,
   const short* __restrict__ wt2b, const float* __restrict__ c2b,
   const short* __restrict__ wt3b, const float* __restrict__ c3b,
   float* __restrict__ pooled){
  __shared__ short fs_b[146*8];   // rows t0-3 .. t0+HT+2 (134 real), rest zero
  __shared__ short h1t[146*64];   // h1 times t0-2+row, rows 0..131 real
  __shared__ short h2t[130*64];   // h2 times t0-1+row, rows 0..129
  int tid  = threadIdx.x;
  int b    = blockIdx.y;
  int t0   = blockIdx.x * HT;
  int lane = tid & 63;
  int w    = tid >> 6;
  int cb   = w*16;
  int lc   = lane & 15, g = lane >> 4;

  for (int task = tid; task < 146*8; task += 256){
    int r = task >> 3, d = task & 7;
    int t = t0 - 3 + r;
    float v = (r < 134 && t >= 0 && t < L) ? f[((size_t)b*L + t)*8 + d] : 0.f;
    fs_b[task] = bfc_(v);
  }
  // zero h1t tail rows 132..145 (read by c2's last tile, outputs discarded)
  for (int i = tid; i < 14*64; i += 256){
    int row = 132 + (i>>6), col = i&63;
    h1t[SW(row, col)] = 0;
  }
  __syncthreads();

  // phase A: c1 via MFMA; h1 cols 0..131 (t1 = t0-2+col)
  {
    bf16x8 a1 = *(const bf16x8*)(wt1b + (cb + lc)*32 + g*8);
    f32x4 bias1 = *(const f32x4*)(c1b + cb + (g<<2));
    #pragma unroll
    for (int nt=0; nt<9; nt++){
      int tcol = nt*16 + lc;
      bf16x8 bv = {0,0,0,0,0,0,0,0};
      if (g < 3) bv = *(bf16x8*)&fs_b[(tcol+g)*8];
      f32x4 acc = {0.f,0.f,0.f,0.f};
      acc = __builtin_amdgcn_mfma_f32_16x16x32_bf16(a1, bv, acc, 0, 0, 0);
      if (tcol < 132){
        int t1 = t0 - 2 + tcol;
        bool v = (t1 >= 0 && t1 < L);
        short4v pk;
        #pragma unroll
        for (int reg=0;reg<4;reg++)
          pk[reg] = bfc_(v ? fmaxf(acc[reg] + bias1[reg], 0.f) : 0.f);
        *(short4v*)&h1t[SW(tcol, cb + (g<<2))] = pk;
      }
    }
  }
  __syncthreads();

  // c2: h2 rows 0..129 (tg = t0-1+tr)
  {
    const short* wA = wt2b + (cb + lc)*192 + g*8;
    bf16x8 a2[6];
    #pragma unroll
    for (int s=0;s<6;s++) a2[s] = *(const bf16x8*)(wA + 32*s);
    f32x4 bias2 = *(const f32x4*)(c2b + cb + (g<<2));
    #pragma unroll
    for (int nt=0; nt<9; nt++){
      f32x4 acc = {0.f,0.f,0.f,0.f};
      #pragma unroll
      for (int s=0;s<6;s++){
        int k = s>>1, ci0 = (s&1)*32;
        int jr = nt*16 + lc + k;
        bf16x8 bfr = *(bf16x8*)&h1t[SW(jr, ci0 + g*8)];
        acc = __builtin_amdgcn_mfma_f32_16x16x32_bf16(a2[s], bfr, acc, 0, 0, 0);
      }
      int tr = nt*16 + lc;
      if (tr < 130){
        int tg = t0 - 1 + tr;
        bool v = (tg >= 0 && tg < L);
        short4v pk;
        #pragma unroll
        for (int reg=0;reg<4;reg++)
          pk[reg] = bfc_(v ? fmaxf(acc[reg] + bias2[reg], 0.f) : 0.f);
        *(short4v*)&h2t[SW(tr, cb + (g<<2))] = pk;
      }
    }
  }
  __syncthreads();

  // c3 + residual relu + pool (t = t0 + nt*16 + lc, 8 tiles = 128 outputs)
  {
    const short* wA = wt3b + (cb + lc)*192 + g*8;
    bf16x8 a3[6];
    #pragma unroll
    for (int s=0;s<6;s++) a3[s] = *(const bf16x8*)(wA + 32*s);
    f32x4 bias3 = *(const f32x4*)(c3b + cb + (g<<2));
    int c0 = cb + (g<<2);
    float pool[4] = {0.f,0.f,0.f,0.f};
    #pragma unroll
    for (int nt=0; nt<8; nt++){
      f32x4 acc = {0.f,0.f,0.f,0.f};
      #pragma unroll
      for (int s=0;s<6;s++){
        int k = s>>1, ci0 = (s&1)*32;
        int jr = nt*16 + lc + k;
        bf16x8 bfr = *(bf16x8*)&h2t[SW(jr, ci0 + g*8)];
        acc = __builtin_amdgcn_mfma_f32_16x16x32_bf16(a3[s], bfr, acc, 0, 0, 0);
      }
      int t = t0 + nt*16 + lc;
      short4v hres = *(short4v*)&h1t[SW(nt*16 + lc + 2, c0)];
      if (t < L){
        #pragma unroll
        for (int reg=0;reg<4;reg++)
          pool[reg] += fmaxf(b2f_(hres[reg]) + acc[reg] + bias3[reg], 0.f);
      }
    }
    #pragma unroll
    for (int m=1; m<16; m<<=1){
      #pragma unroll
      for (int reg=0;reg<4;reg++) pool[reg] += __shfl_xor(pool[reg], m, 64);
    }
    if (lc == 0){
      #pragma unroll
      for (int reg=0;reg<4;reg++) atomicAdd(&pooled[b*64 + c0 + reg], pool[reg]);
    }
  }
}

// ---------------- final FC ----------------
__global__ void k_fc(const float* __restrict__ pooled, const float* __restrict__ fcw,
                     const float* __restrict__ fcb, float* __restrict__ out){
  int gid = blockIdx.x*256 + threadIdx.x;
  if (gid >= B*230) return;
  int b = gid / 230, j = gid % 230;
  const float* p = pooled + b*64;
  const float* wv = fcw + j*64;
  float a = 0.f;
  #pragma unroll
  for (int c=0;c<64;c++) a += p[c]*wv[c];
  out[gid] = a*(1.f/(float)L) + fcb[j];
}

extern "C" void kernel_launch(void* const* d_in, const int* in_sizes, int n_in,
                              void* d_out, int out_size, void* d_ws, size_t ws_size,
                              hipStream_t stream){
  const float* x      = (const float*)d_in[0];
  const int*   idx    = (const int*)  d_in[1];
  const float* embed  = (const float*)d_in[2];
  const float* norm_w = (const float*)d_in[3];
  const float* in_proj= (const float*)d_in[4];
  const float* conv_w = (const float*)d_in[5];
  const float* conv_b = (const float*)d_in[6];
  const float* x_proj = (const float*)d_in[7];
  const float* dt_w   = (const float*)d_in[8];
  const float* dt_b   = (const float*)d_in[9];
  const float* A_log  = (const float*)d_in[10];
  const float* Dp     = (const float*)d_in[11];
  const float* out_w  = (const float*)d_in[12];
  const float* c1w    = (const float*)d_in[13];
  const float* c1b    = (const float*)d_in[14];
  const float* c2w    = (const float*)d_in[15];
  const float* c2b    = (const float*)d_in[16];
  const float* c3w    = (const float*)d_in[17];
  const float* c3b    = (const float*)d_in[18];
  const float* fcw    = (const float*)d_in[19];
  const float* fcb    = (const float*)d_in[20];
  float* out = (float*)d_out;

  float* ws = (float*)d_ws;
  float* f0     = ws;                 // 5,120,000
  float* f1     = f0 + 5120000;       // 5,120,000
  float* Sc     = f1 + 5120000;       // 1,638,400
  float* Pc     = Sc + 1638400;       // 1,638,400
  float* pooled = Pc + 1638400;       // 8,192
  short* wt1b   = (short*)(pooled + 8192);  // 2,048 shorts
  short* wt2b   = wt1b + 2048;              // 12,288 shorts
  short* wt3b   = wt2b + 12288;             // 12,288 shorts

  k_wt<<<104,256,0,stream>>>(c1w, c2w, c3w, wt1b, wt2b, wt3b);
  k_embed<<<2500,256,0,stream>>>(x, idx, embed, f0);
  for (int l=0;l<NL;l++){
    const float* fin = (l & 1) ? f1 : f0;
    float*       fo  = (l & 1) ? f0 : f1;
    k_l1<<<dim3(NCH,B),256,0,stream>>>(fin, norm_w + l*8, in_proj + l*256, conv_w + l*48,
         conv_b + l*16, x_proj + l*528, dt_w + l*16, dt_b + l*16, A_log + l*256, Sc, Pc);
    k_l3<<<dim3(NCH,B),256,0,stream>>>(fin, fo, norm_w + l*8, in_proj + l*256, conv_w + l*48,
         conv_b + l*16, x_proj + l*528, dt_w + l*16, dt_b + l*16, A_log + l*256,
         Dp + l*16, Sc, Pc, out_w + l*128);
  }
  (void)hipMemsetAsync(pooled, 0, B*64*sizeof(float), stream);
  k_head<<<dim3((L+HT-1)/HT,B),256,0,stream>>>(f0, wt1b, c1b, wt2b, c2b, wt3b, c3b, pooled);
  k_fc<<<(B*230+255)/256,256,0,stream>>>(pooled, fcw, fcb, out);
}

// Round 12
// 1146.037 us; speedup vs baseline: 10.0613x; 1.0621x over previous
//
#include <hip/hip_runtime.h>
#include <math.h>

#define B 128
#define L 5000
#define NL 4
#define NCH 50
#define LC 100
#define ST 50
#define HT 128

typedef __attribute__((ext_vector_type(8))) short bf16x8;
typedef __attribute__((ext_vector_type(4))) short short4v;
typedef __attribute__((ext_vector_type(4))) float f32x4;

__device__ __forceinline__ float sigmoidf_(float x){ return 1.f/(1.f+__expf(-x)); }
__device__ __forceinline__ float siluf_(float x){ return x*sigmoidf_(x); }
__device__ __forceinline__ float softplusf_(float x){ return fmaxf(x,0.f) + log1pf(__expf(-fabsf(x))); }
__device__ __forceinline__ short bfc_(float x){
  union { float f; unsigned u; } v; v.f = x;
  unsigned r = v.u + 0x7fffu + ((v.u >> 16) & 1u);
  return (short)(r >> 16);
}
__device__ __forceinline__ float b2f_(short s){
  union { unsigned u; float f; } v; v.u = ((unsigned)(unsigned short)s) << 16;
  return v.f;
}
#define SW(row, col) (((row)<<6) + ((col) ^ (((row)&7)<<3)))

// ---------------- f0 = embed[idx] * x ----------------
__global__ void k_embed(const float* __restrict__ x, const int* __restrict__ idx,
                        const float* __restrict__ embed, float* __restrict__ f){
  int gid = blockIdx.x*256 + threadIdx.x;
  if (gid >= B*L) return;
  int t = gid % L;
  float xv = x[gid];
  const float* er = embed + (size_t)idx[t]*8;
  float4 e0 = *(const float4*)(er);
  float4 e1 = *(const float4*)(er+4);
  *(float4*)(f + (size_t)gid*8)   = make_float4(e0.x*xv, e0.y*xv, e0.z*xv, e0.w*xv);
  *(float4*)(f + (size_t)gid*8+4) = make_float4(e1.x*xv, e1.y*xv, e1.z*xv, e1.w*xv);
}

// ---------------- pass 1: full preprocess (u,sz,B,C,dl) -> global + per-chunk scan -> Sc,Pc ----------------
__global__ __launch_bounds__(256,4) void k_l1(const float* __restrict__ fin,
    const float* __restrict__ norm_w, const float* __restrict__ in_proj,
    const float* __restrict__ conv_w, const float* __restrict__ conv_b,
    const float* __restrict__ x_proj, const float* __restrict__ dt_w,
    const float* __restrict__ dt_b, const float* __restrict__ A_log,
    float* __restrict__ Sc, float* __restrict__ Pc,
    float2* __restrict__ duA, float2* __restrict__ BCA, float* __restrict__ szA){
  __shared__ float fsub[52][8], rn[52];
  __shared__ float uL[ST][17];
  __shared__ float2 duL[ST][16];
  __shared__ float BLs[ST][17];
  __shared__ float dbc0[ST];
  int tid = threadIdx.x, ch = blockIdx.x, b = blockIdx.y;
  int e = tid>>4, n = tid&15;
  int ct = tid&15;
  float ipnw_c[8], ipnwz_c[8], cwc[3];
  #pragma unroll
  for (int d=0;d<8;d++){
    ipnw_c[d]  = in_proj[ct*8+d]*norm_w[d];
    ipnwz_c[d] = in_proj[(16+ct)*8+d]*norm_w[d];
  }
  #pragma unroll
  for (int k=0;k<3;k++) cwc[k] = conv_w[ct*3+k];
  float cbc = conv_b[ct];
  float xp0_c = x_proj[ct];
  float xpB_r[16], xpC_r[16];
  #pragma unroll
  for (int k=0;k<16;k++){
    xpB_r[k] = x_proj[(1+ct)*16+k];
    xpC_r[k] = x_proj[(17+ct)*16+k];
  }
  float dtw_e = dt_w[ct], dtb_e = dt_b[ct];
  float a = -__expf(A_log[e*16+n]);
  float h = 0.f, dsum = 0.f;
  int t00 = ch*LC;
  for (int sub=0; sub<LC/ST; sub++){
    int ts = t00 + sub*ST;
    __syncthreads();
    for (int i=tid;i<104;i+=256){ int r=i>>1, half=i&1; int t=ts-2+r;
      *(float4*)&fsub[r][half*4] = (t>=0) ? *(const float4*)&fin[((size_t)b*L+t)*8+half*4]
                                          : make_float4(0.f,0.f,0.f,0.f); }
    __syncthreads();
    if (tid < 52){ float ss=0.f;
      #pragma unroll
      for (int d=0;d<8;d++){ float v=fsub[tid][d]; ss += v*v; }
      rn[tid] = rsqrtf(ss*0.125f + 1e-5f); }
    __syncthreads();
    // u + sz + dbc0
    for (int i=tid;i<ST*16;i+=256){ int j=i>>4;
      float acc = cbc;
      #pragma unroll
      for (int kk=0;kk<3;kk++){
        int r = j + kk;
        float dot=0.f;
        #pragma unroll
        for (int d=0;d<8;d++) dot += ipnw_c[d]*fsub[r][d];
        acc += cwc[kk]*(dot*rn[r]);
      }
      float uv = siluf_(acc);
      uL[j][ct] = uv;
      int r2 = j + 2;
      float dz=0.f;
      #pragma unroll
      for (int d=0;d<8;d++) dz += ipnwz_c[d]*fsub[r2][d];
      szA[((size_t)b*L + ts + j)*16 + ct] = siluf_(dz*rn[r2]);
      float pp = xp0_c*uv;
      pp += __shfl_xor(pp, 1, 64);
      pp += __shfl_xor(pp, 2, 64);
      pp += __shfl_xor(pp, 4, 64);
      pp += __shfl_xor(pp, 8, 64);
      if (ct == 0) dbc0[j] = pp;
    }
    __syncthreads();
    // B,C + dl + global stores
    for (int i=tid;i<ST*16;i+=256){ int j=i>>4;
      float accB=0.f, accC=0.f;
      #pragma unroll
      for (int c=0;c<16;c++){
        float uv2 = uL[j][c];
        accB += xpB_r[c]*uv2;
        accC += xpC_r[c]*uv2;
      }
      BLs[j][ct] = accB;
      float dd = softplusf_(dbc0[j]*dtw_e + dtb_e);
      float uv = uL[j][ct];
      duL[j][ct] = make_float2(dd, dd*uv);
      size_t gi = ((size_t)b*L + ts + j)*16 + ct;
      BCA[gi] = make_float2(accB, accC);
      duA[gi] = make_float2(dd, uv);
    }
    __syncthreads();
    for (int j=0;j<ST;j++){
      float2 du = duL[j][e];
      float bb = BLs[j][n];
      h = __expf(du.x*a)*h + du.y*bb;
      dsum += du.x;
    }
  }
  size_t o = ((size_t)b*NCH + ch)*256 + tid;
  Sc[o] = h;
  Pc[o] = __expf(a*dsum);
}

// ---------------- pass 3: load intermediates + h0 prefix + scan + gated out_proj ----------------
__global__ __launch_bounds__(256,4) void k_l3(const float* __restrict__ fin, float* __restrict__ fout,
    const float* __restrict__ A_log, const float* __restrict__ Dp,
    const float* __restrict__ Sc, const float* __restrict__ Pc,
    const float* __restrict__ ow,
    const float2* __restrict__ duA, const float2* __restrict__ BCA,
    const float* __restrict__ szA){
  __shared__ float2 duL[ST*16], BCL[ST*16];
  __shared__ float uLs[ST*16], szL[ST*16], yL[ST*16];
  __shared__ float hcL[10*320];
  __shared__ float s_owp[8*17], s_De[16];
  int tid = threadIdx.x, ch = blockIdx.x, b = blockIdx.y;
  int e = tid>>4, n = tid&15;
  int dt8 = tid&7;
  float a = -__expf(A_log[e*16+n]);
  if (tid < 128) s_owp[(tid>>4)*17 + (tid&15)] = ow[tid];
  if (tid < 16) s_De[tid] = Dp[tid];
  float h = 0.f;
  for (int c2=0; c2<ch; c2++){
    size_t o = ((size_t)b*NCH + c2)*256 + tid;
    h = Pc[o]*h + Sc[o];
  }
  int t00 = ch*LC;
  for (int sub=0; sub<LC/ST; sub++){
    int ts = t00 + sub*ST;
    __syncthreads();
    // stage intermediates: 800 elements each
    const f32x4* duG = (const f32x4*)(duA + ((size_t)b*L + ts)*16);
    const f32x4* bcG = (const f32x4*)(BCA + ((size_t)b*L + ts)*16);
    for (int i=tid;i<400;i+=256){
      f32x4 v = duG[i];
      int bidx = i*2;
      duL[bidx]   = make_float2(v[0], v[0]*v[1]);
      duL[bidx+1] = make_float2(v[2], v[2]*v[3]);
      uLs[bidx]   = v[1];
      uLs[bidx+1] = v[3];
      f32x4 wv = bcG[i];
      BCL[bidx]   = make_float2(wv[0], wv[1]);
      BCL[bidx+1] = make_float2(wv[2], wv[3]);
    }
    const f32x4* szG = (const f32x4*)(szA + ((size_t)b*L + ts)*16);
    for (int i=tid;i<200;i+=256){
      *(f32x4*)&szL[i*4] = szG[i];
    }
    __syncthreads();
    // scan + deferred reduce
    for (int q=0; q<ST/10; q++){
      #pragma unroll
      for (int j2=0; j2<10; j2++){
        int j = q*10 + j2;
        float2 du = duL[j*16+e];
        float2 bc = BCL[j*16+n];
        h = __expf(du.x*a)*h + du.y*bc.x;
        hcL[j2*320 + e*20 + n] = h*bc.y;
      }
      __syncthreads();
      if (tid < 160){
        int jj = tid>>4, ee = tid&15;
        int j = q*10 + jj;
        const f32x4* hp = (const f32x4*)&hcL[jj*320 + ee*20];
        f32x4 p0 = hp[0], p1 = hp[1], p2 = hp[2], p3 = hp[3];
        float s = ((p0[0]+p0[1])+(p0[2]+p0[3])) + ((p1[0]+p1[1])+(p1[2]+p1[3]))
                + ((p2[0]+p2[1])+(p2[2]+p2[3])) + ((p3[0]+p3[1])+(p3[2]+p3[3]));
        yL[j*16+ee] = (s + s_De[ee]*uLs[j*16+ee]) * szL[j*16+ee];
      }
      __syncthreads();
    }
    // out_proj + residual (fin read direct)
    for (int i=tid;i<ST*8;i+=256){ int j=i>>3;
      size_t fi = ((size_t)b*L + ts + j)*8 + dt8;
      float acc = fin[fi];
      f32x4 y0 = *(const f32x4*)&yL[j*16];
      f32x4 y1 = *(const f32x4*)&yL[j*16+4];
      f32x4 y2 = *(const f32x4*)&yL[j*16+8];
      f32x4 y3 = *(const f32x4*)&yL[j*16+12];
      #pragma unroll
      for (int c=0;c<4;c++)
        acc += s_owp[dt8*17+c]*y0[c] + s_owp[dt8*17+4+c]*y1[c]
             + s_owp[dt8*17+8+c]*y2[c] + s_owp[dt8*17+12+c]*y3[c];
      fout[fi] = acc;
    }
  }
}

// ---------------- head weight prep ----------------
__global__ void k_wt(const float* __restrict__ c1w, const float* __restrict__ c2w,
                     const float* __restrict__ c3w, short* __restrict__ wt1b,
                     short* __restrict__ wt2b, short* __restrict__ wt3b){
  int idx = blockIdx.x*256 + threadIdx.x;
  if (idx < 2048){
    int c = idx >> 5, m = idx & 31;
    int kk = m >> 3, d = m & 7;
    wt1b[idx] = (kk < 3) ? bfc_(c1w[c*24 + d*3 + kk]) : (short)0;
  } else if (idx < 2048 + 12288){
    int i = idx - 2048;
    int c = i / 192, rem = i % 192;
    int k = rem >> 6, ci = rem & 63;
    wt2b[i] = bfc_(c2w[c*192 + ci*3 + k]);
  } else if (idx < 2048 + 24576){
    int i = idx - 2048 - 12288;
    int c = i / 192, rem = i % 192;
    int k = rem >> 6, ci = rem & 63;
    wt3b[i] = bfc_(c3w[c*192 + ci*3 + k]);
  }
}

// ---------------- fused head, HT=128 tile ----------------
__global__ __launch_bounds__(256) void k_head(const float* __restrict__ f,
   const short* __restrict__ wt1b, const float* __restrict__ c1b,
   const short* __restrict__ wt2b, const float* __restrict__ c2b,
   const short* __restrict__ wt3b, const float* __restrict__ c3b,
   float* __restrict__ pooled){
  __shared__ short fs_b[146*8];
  __shared__ short h1t[146*64];
  __shared__ short h2t[130*64];
  int tid  = threadIdx.x;
  int b    = blockIdx.y;
  int t0   = blockIdx.x * HT;
  int lane = tid & 63;
  int w    = tid >> 6;
  int cb   = w*16;
  int lc   = lane & 15, g = lane >> 4;

  for (int task = tid; task < 146*8; task += 256){
    int r = task >> 3, d = task & 7;
    int t = t0 - 3 + r;
    float v = (r < 134 && t >= 0 && t < L) ? f[((size_t)b*L + t)*8 + d] : 0.f;
    fs_b[task] = bfc_(v);
  }
  for (int i = tid; i < 14*64; i += 256){
    int row = 132 + (i>>6), col = i&63;
    h1t[SW(row, col)] = 0;
  }
  __syncthreads();

  {
    bf16x8 a1 = *(const bf16x8*)(wt1b + (cb + lc)*32 + g*8);
    f32x4 bias1 = *(const f32x4*)(c1b + cb + (g<<2));
    #pragma unroll
    for (int nt=0; nt<9; nt++){
      int tcol = nt*16 + lc;
      bf16x8 bv = {0,0,0,0,0,0,0,0};
      if (g < 3) bv = *(bf16x8*)&fs_b[(tcol+g)*8];
      f32x4 acc = {0.f,0.f,0.f,0.f};
      acc = __builtin_amdgcn_mfma_f32_16x16x32_bf16(a1, bv, acc, 0, 0, 0);
      if (tcol < 132){
        int t1 = t0 - 2 + tcol;
        bool v = (t1 >= 0 && t1 < L);
        short4v pk;
        #pragma unroll
        for (int reg=0;reg<4;reg++)
          pk[reg] = bfc_(v ? fmaxf(acc[reg] + bias1[reg], 0.f) : 0.f);
        *(short4v*)&h1t[SW(tcol, cb + (g<<2))] = pk;
      }
    }
  }
  __syncthreads();

  {
    const short* wA = wt2b + (cb + lc)*192 + g*8;
    bf16x8 a2[6];
    #pragma unroll
    for (int s=0;s<6;s++) a2[s] = *(const bf16x8*)(wA + 32*s);
    f32x4 bias2 = *(const f32x4*)(c2b + cb + (g<<2));
    #pragma unroll
    for (int nt=0; nt<9; nt++){
      f32x4 acc = {0.f,0.f,0.f,0.f};
      #pragma unroll
      for (int s=0;s<6;s++){
        int k = s>>1, ci0 = (s&1)*32;
        int jr = nt*16 + lc + k;
        bf16x8 bfr = *(bf16x8*)&h1t[SW(jr, ci0 + g*8)];
        acc = __builtin_amdgcn_mfma_f32_16x16x32_bf16(a2[s], bfr, acc, 0, 0, 0);
      }
      int tr = nt*16 + lc;
      if (tr < 130){
        int tg = t0 - 1 + tr;
        bool v = (tg >= 0 && tg < L);
        short4v pk;
        #pragma unroll
        for (int reg=0;reg<4;reg++)
          pk[reg] = bfc_(v ? fmaxf(acc[reg] + bias2[reg], 0.f) : 0.f);
        *(short4v*)&h2t[SW(tr, cb + (g<<2))] = pk;
      }
    }
  }
  __syncthreads();

  {
    const short* wA = wt3b + (cb + lc)*192 + g*8;
    bf16x8 a3[6];
    #pragma unroll
    for (int s=0;s<6;s++) a3[s] = *(const bf16x8*)(wA + 32*s);
    f32x4 bias3 = *(const f32x4*)(c3b + cb + (g<<2));
    int c0 = cb + (g<<2);
    float pool[4] = {0.f,0.f,0.f,0.f};
    #pragma unroll
    for (int nt=0; nt<8; nt++){
      f32x4 acc = {0.f,0.f,0.f,0.f};
      #pragma unroll
      for (int s=0;s<6;s++){
        int k = s>>1, ci0 = (s&1)*32;
        int jr = nt*16 + lc + k;
        bf16x8 bfr = *(bf16x8*)&h2t[SW(jr, ci0 + g*8)];
        acc = __builtin_amdgcn_mfma_f32_16x16x32_bf16(a3[s], bfr, acc, 0, 0, 0);
      }
      int t = t0 + nt*16 + lc;
      short4v hres = *(short4v*)&h1t[SW(nt*16 + lc + 2, c0)];
      if (t < L){
        #pragma unroll
        for (int reg=0;reg<4;reg++)
          pool[reg] += fmaxf(b2f_(hres[reg]) + acc[reg] + bias3[reg], 0.f);
      }
    }
    #pragma unroll
    for (int m=1; m<16; m<<=1){
      #pragma unroll
      for (int reg=0;reg<4;reg++) pool[reg] += __shfl_xor(pool[reg], m, 64);
    }
    if (lc == 0){
      #pragma unroll
      for (int reg=0;reg<4;reg++) atomicAdd(&pooled[b*64 + c0 + reg], pool[reg]);
    }
  }
}

// ---------------- final FC ----------------
__global__ void k_fc(const float* __restrict__ pooled, const float* __restrict__ fcw,
                     const float* __restrict__ fcb, float* __restrict__ out){
  int gid = blockIdx.x*256 + threadIdx.x;
  if (gid >= B*230) return;
  int b = gid / 230, j = gid % 230;
  const float* p = pooled + b*64;
  const float* wv = fcw + j*64;
  float a = 0.f;
  #pragma unroll
  for (int c=0;c<64;c++) a += p[c]*wv[c];
  out[gid] = a*(1.f/(float)L) + fcb[j];
}

extern "C" void kernel_launch(void* const* d_in, const int* in_sizes, int n_in,
                              void* d_out, int out_size, void* d_ws, size_t ws_size,
                              hipStream_t stream){
  const float* x      = (const float*)d_in[0];
  const int*   idx    = (const int*)  d_in[1];
  const float* embed  = (const float*)d_in[2];
  const float* norm_w = (const float*)d_in[3];
  const float* in_proj= (const float*)d_in[4];
  const float* conv_w = (const float*)d_in[5];
  const float* conv_b = (const float*)d_in[6];
  const float* x_proj = (const float*)d_in[7];
  const float* dt_w   = (const float*)d_in[8];
  const float* dt_b   = (const float*)d_in[9];
  const float* A_log  = (const float*)d_in[10];
  const float* Dp     = (const float*)d_in[11];
  const float* out_w  = (const float*)d_in[12];
  const float* c1w    = (const float*)d_in[13];
  const float* c1b    = (const float*)d_in[14];
  const float* c2w    = (const float*)d_in[15];
  const float* c2b    = (const float*)d_in[16];
  const float* c3w    = (const float*)d_in[17];
  const float* c3b    = (const float*)d_in[18];
  const float* fcw    = (const float*)d_in[19];
  const float* fcb    = (const float*)d_in[20];
  float* out = (float*)d_out;

  // workspace: 64.74M floats = 259 MB (r1 proved 266 MB works; r2 crashed at 269)
  float* ws = (float*)d_ws;
  float* f0     = ws;                 // 5,120,000
  float* f1     = f0 + 5120000;       // 5,120,000
  float* Sc     = f1 + 5120000;       // 1,638,400
  float* Pc     = Sc + 1638400;       // 1,638,400
  float* pooled = Pc + 1638400;       // 8,192
  float2* duA   = (float2*)(pooled + 8192);   // 10,240,000 float2
  float2* BCA   = duA + 10240000;             // 10,240,000 float2
  float* szA    = (float*)(BCA + 10240000);   // 10,240,000
  short* wt1b   = (short*)(szA + 10240000);   // 2,048 shorts
  short* wt2b   = wt1b + 2048;                // 12,288
  short* wt3b   = wt2b + 12288;               // 12,288

  k_wt<<<104,256,0,stream>>>(c1w, c2w, c3w, wt1b, wt2b, wt3b);
  k_embed<<<2500,256,0,stream>>>(x, idx, embed, f0);
  for (int l=0;l<NL;l++){
    const float* fin = (l & 1) ? f1 : f0;
    float*       fo  = (l & 1) ? f0 : f1;
    k_l1<<<dim3(NCH,B),256,0,stream>>>(fin, norm_w + l*8, in_proj + l*256, conv_w + l*48,
         conv_b + l*16, x_proj + l*528, dt_w + l*16, dt_b + l*16, A_log + l*256,
         Sc, Pc, duA, BCA, szA);
    k_l3<<<dim3(NCH,B),256,0,stream>>>(fin, fo, A_log + l*256, Dp + l*16, Sc, Pc,
         out_w + l*128, duA, BCA, szA);
  }
  (void)hipMemsetAsync(pooled, 0, B*64*sizeof(float), stream);
  k_head<<<dim3((L+HT-1)/HT,B),256,0,stream>>>(f0, wt1b, c1b, wt2b, c2b, wt3b, c3b, pooled);
  k_fc<<<(B*230+255)/256,256,0,stream>>>(pooled, fcw, fcb, out);
}